// Round 5
// baseline (1542.552 us; speedup 1.0000x reference)
//
#include <hip/hip_runtime.h>

#define D 128
#define CE 8192          // edges per sort chunk
#define NB_MAX 1024      // max node buckets (128 nodes each) -> nNodes <= 130944
#define MAXC 512         // max chunks supported by agg kernel
#define CHUNK 1024       // legacy tier-2 scan chunk

// out = relu( (sum_e a_e * x[src_e]) @ W + y + bias )   [linearity of GEMM]
// Round 5: block-local chunk sort (coalesced writes only) + LDS-tile
// accumulate fused with the GEMM epilogue. No global scatter, no fp32 atomics.

__device__ __forceinline__ unsigned short f2bf(float f) {
  unsigned u = __float_as_uint(f);
  unsigned r = (u + 0x7fffu + ((u >> 16) & 1u)) >> 16;  // RNE
  return (unsigned short)r;
}

// ===================== K1: x -> bf16 table =================================
__global__ __launch_bounds__(256) void convert_kernel(
    const float4* __restrict__ x4, ushort4* __restrict__ xb4, int n4) {
  int i = blockIdx.x * 256 + threadIdx.x;
  if (i < n4) {
    float4 v = x4[i];
    ushort4 r;
    r.x = f2bf(v.x);
    r.y = f2bf(v.y);
    r.z = f2bf(v.z);
    r.w = f2bf(v.w);
    xb4[i] = r;
  }
}

// ===================== K2: block-local counting sort =======================
// Each block sorts its CE-edge chunk by bucket (dst>>7) in LDS, writes the
// sorted chunk coalesced to edges[c*CE ...], and bucket starts (ushort) to
// ofs[c*(nB+1) ...]. Record: int2{ src | (dst&127)<<17 , bits(adj) }.
__global__ __launch_bounds__(256) void chunk_sort_kernel(
    const int* __restrict__ src, const int* __restrict__ dst,
    const float* __restrict__ adj, int2* __restrict__ edges,
    unsigned short* __restrict__ ofs, int nE, int nB) {
  __shared__ int2 stage[CE];       // 64 KB
  __shared__ int h[NB_MAX + 4];    // hist -> starts -> cursors
  __shared__ int tsum[256];
  const int t = threadIdx.x;
  const int c = blockIdx.x;
  const int e0 = c * CE;
  const int n = min(CE, nE - e0);

  for (int i = t; i < NB_MAX + 4; i += 256) h[i] = 0;
  __syncthreads();

  for (int i = t; i < n; i += 256) atomicAdd(&h[dst[e0 + i] >> 7], 1);
  __syncthreads();

  // exclusive scan over 1024 entries (4 per thread + block H-S scan)
  const int base = t * 4;
  int v0 = h[base], v1 = h[base + 1], v2 = h[base + 2], v3 = h[base + 3];
  int s = v0 + v1 + v2 + v3;
  tsum[t] = s;
  __syncthreads();
  for (int off = 1; off < 256; off <<= 1) {
    int u = (t >= off) ? tsum[t - off] : 0;
    __syncthreads();
    tsum[t] += u;
    __syncthreads();
  }
  int excl = tsum[t] - s;
  h[base] = excl;
  h[base + 1] = excl + v0;
  h[base + 2] = excl + v0 + v1;
  h[base + 3] = excl + v0 + v1 + v2;
  __syncthreads();

  // publish bucket starts (h[nB] == n: all buckets >= nB are empty)
  unsigned short* o = ofs + (size_t)c * (nB + 1);
  for (int i = t; i <= nB; i += 256) o[i] = (unsigned short)h[i];
  __syncthreads();

  // scatter into LDS stage via per-bucket cursors
  for (int i = t; i < n; i += 256) {
    int e = e0 + i;
    int d = dst[e];
    int pos = atomicAdd(&h[d >> 7], 1);
    int2 ev;
    ev.x = src[e] | ((d & 127) << 17);
    ev.y = __float_as_int(adj[e]);
    stage[pos] = ev;
  }
  __syncthreads();

  // coalesced write-out
  for (int i = t; i < n; i += 256) edges[e0 + i] = stage[i];
}

// ===================== K3: accumulate tile + fused GEMM ====================
// Block b owns nodes [b*128, b*128+128). Phase B: per edge, one wave gathers
// the 256B bf16 x-row (lane l -> cols 2l,2l+1) and ds_add_f32 into the LDS
// tile (lanes l,l+16 share a bank: 2-way = free). Phase C: tile @ W + y + b,
// relu, straight to out. The [N,128] aggregate never touches HBM.
__global__ __launch_bounds__(512) void agg_gemm_kernel(
    const unsigned* __restrict__ xb, const int2* __restrict__ edges,
    const unsigned short* __restrict__ ofs, const float* __restrict__ w,
    const float* __restrict__ y, const float* __restrict__ bias,
    float* __restrict__ out, int nC, int nB, int nNodes) {
  __shared__ float acc[128 * 128];  // 64 KB
  __shared__ int segs[2 * MAXC];    // 4 KB: (abs start, count) per chunk
  const int t = threadIdx.x;
  const int b = blockIdx.x;

  float4* acc4 = (float4*)acc;
  for (int i = t; i < 128 * 32; i += 512) acc4[i] = make_float4(0.f, 0.f, 0.f, 0.f);
  for (int c = t; c < nC; c += 512) {
    int s0 = ofs[(size_t)c * (nB + 1) + b];
    int s1 = ofs[(size_t)c * (nB + 1) + b + 1];
    segs[2 * c] = c * CE + s0;
    segs[2 * c + 1] = s1 - s0;
  }
  __syncthreads();

  const int wv = t >> 6;
  const int l = t & 63;
  for (int c = wv; c < nC; c += 8) {
    int st = segs[2 * c], cnt = segs[2 * c + 1];
    if (cnt <= 0) continue;
    int2 ev = edges[st];
    for (int j = 0; j < cnt; ++j) {
      int2 evn;
      if (j + 1 < cnt) evn = edges[st + j + 1];
      int sp = ev.x;
      float a = __int_as_float(ev.y);
      unsigned v = xb[(size_t)(sp & 0x1FFFF) * 64 + l];
      int ldst = sp >> 17;
      atomicAdd(&acc[ldst * 128 + 2 * l], a * __uint_as_float(v << 16));
      atomicAdd(&acc[ldst * 128 + 2 * l + 1], a * __uint_as_float(v & 0xffff0000u));
      ev = evn;
    }
  }
  __syncthreads();

  // Phase C: 512 thr = 32 colgroups x 16 rowslots; each thread 8 rows.
  const int node0 = b << 7;
  const int cg = t & 31;
  const int rs = t >> 5;
  const float4* w4 = (const float4*)w;
  const float4* y4 = (const float4*)y;
  float4 bv = ((const float4*)bias)[cg];
  float4 o[8];
#pragma unroll
  for (int r = 0; r < 8; ++r) o[r] = make_float4(0.f, 0.f, 0.f, 0.f);
  for (int k = 0; k < D; ++k) {
    float4 wvv = w4[k * 32 + cg];
#pragma unroll
    for (int r = 0; r < 8; ++r) {
      float xv = acc[(rs + 16 * r) * 128 + k];
      o[r].x = fmaf(xv, wvv.x, o[r].x);
      o[r].y = fmaf(xv, wvv.y, o[r].y);
      o[r].z = fmaf(xv, wvv.z, o[r].z);
      o[r].w = fmaf(xv, wvv.w, o[r].w);
    }
  }
  float4* out4 = (float4*)out;
#pragma unroll
  for (int r = 0; r < 8; ++r) {
    int row = node0 + rs + 16 * r;
    if (row < nNodes) {
      float4 yv = y4[(size_t)row * 32 + cg];
      float4 res;
      res.x = fmaxf(o[r].x + yv.x + bv.x, 0.f);
      res.y = fmaxf(o[r].y + yv.y + bv.y, 0.f);
      res.z = fmaxf(o[r].z + yv.z + bv.z, 0.f);
      res.w = fmaxf(o[r].w + yv.w + bv.w, 0.f);
      out4[(size_t)row * 32 + cg] = res;
    }
  }
}

// ======================= tier-2/3 fallbacks (proven) =======================
__global__ __launch_bounds__(256) void zero_counts_kernel(int* __restrict__ c, int n) {
  int i = blockIdx.x * 256 + threadIdx.x;
  if (i < n) c[i] = 0;
}

__global__ __launch_bounds__(256) void hist_kernel(
    const int* __restrict__ dst, int* __restrict__ counts, int nE) {
  int e = blockIdx.x * 256 + threadIdx.x;
  if (e < nE) atomicAdd(&counts[dst[e]], 1);
}

__global__ __launch_bounds__(256) void scan_partial_kernel(
    const int* __restrict__ counts, int* __restrict__ chunk_sum, int n) {
  __shared__ int sdata[256];
  int b = blockIdx.x, t = threadIdx.x;
  int base = b * CHUNK + t * 4;
  int s = 0;
#pragma unroll
  for (int k = 0; k < 4; ++k) {
    int i = base + k;
    if (i < n) s += counts[i];
  }
  sdata[t] = s;
  __syncthreads();
  for (int off = 128; off > 0; off >>= 1) {
    if (t < off) sdata[t] += sdata[t + off];
    __syncthreads();
  }
  if (t == 0) chunk_sum[b] = sdata[0];
}

__global__ void scan_chunks_kernel(const int* __restrict__ chunk_sum,
                                   int* __restrict__ chunk_off,
                                   int* __restrict__ row_start, int nchunks, int n) {
  if (threadIdx.x == 0 && blockIdx.x == 0) {
    int run = 0;
    for (int i = 0; i < nchunks; ++i) {
      chunk_off[i] = run;
      run += chunk_sum[i];
    }
    row_start[n] = run;
  }
}

__global__ __launch_bounds__(256) void scan_final_kernel(
    const int* __restrict__ counts, const int* __restrict__ chunk_off,
    int* __restrict__ row_start, int* __restrict__ cursor, int n) {
  __shared__ int sdata[256];
  int b = blockIdx.x, t = threadIdx.x;
  int base = b * CHUNK + t * 4;
  int c[4] = {0, 0, 0, 0};
#pragma unroll
  for (int k = 0; k < 4; ++k) {
    int i = base + k;
    if (i < n) c[k] = counts[i];
  }
  int tsum = c[0] + c[1] + c[2] + c[3];
  sdata[t] = tsum;
  __syncthreads();
  for (int off = 1; off < 256; off <<= 1) {
    int v = (t >= off) ? sdata[t - off] : 0;
    __syncthreads();
    sdata[t] += v;
    __syncthreads();
  }
  int run = sdata[t] - tsum + chunk_off[b];
#pragma unroll
  for (int k = 0; k < 4; ++k) {
    int i = base + k;
    if (i < n) {
      row_start[i] = run;
      cursor[i] = run;
      run += c[k];
    }
  }
}

__global__ __launch_bounds__(256) void scatter_sort_kernel(
    const int* __restrict__ src, const int* __restrict__ dst,
    const float* __restrict__ adj, int* __restrict__ cursor,
    int2* __restrict__ edges, int nE) {
  int e = blockIdx.x * 256 + threadIdx.x;
  if (e >= nE) return;
  int d = dst[e];
  int2 ev;
  ev.x = src[e];
  ev.y = __float_as_int(adj[e]);
  int pos = atomicAdd(&cursor[d], 1);
  edges[pos] = ev;
}

__global__ __launch_bounds__(256) void gather_fp32_kernel(
    const float* __restrict__ x, const int* __restrict__ row_start,
    const int2* __restrict__ edges, float* __restrict__ out, int nNodes) {
  int g = (blockIdx.x * 256 + threadIdx.x) >> 5;
  int q = threadIdx.x & 31;
  if (g >= nNodes) return;
  int beg = row_start[g], end = row_start[g + 1];
  const float4* x4 = (const float4*)x;
  float4 acc = make_float4(0.f, 0.f, 0.f, 0.f);
  for (int j = beg; j < end; ++j) {
    int2 e0 = edges[j];
    float a0 = __int_as_float(e0.y);
    float4 v0 = x4[(size_t)e0.x * 32 + q];
    acc.x = fmaf(a0, v0.x, acc.x);
    acc.y = fmaf(a0, v0.y, acc.y);
    acc.z = fmaf(a0, v0.z, acc.z);
    acc.w = fmaf(a0, v0.w, acc.w);
  }
  ((float4*)out)[(size_t)g * 32 + q] = acc;
}

__global__ __launch_bounds__(256) void zero_kernel(float4* __restrict__ out, int n4) {
  int i = blockIdx.x * 256 + threadIdx.x;
  if (i < n4) out[i] = make_float4(0.f, 0.f, 0.f, 0.f);
}

__global__ __launch_bounds__(256) void scatter_atomic_kernel(
    const float* __restrict__ x, const int* __restrict__ src,
    const int* __restrict__ dst, const float* __restrict__ adj,
    float* __restrict__ out, int nE) {
  int tid = blockIdx.x * 256 + threadIdx.x;
  int e = tid >> 5;
  int q = tid & 31;
  if (e >= nE) return;
  int s = src[e];
  int d = dst[e];
  float a = adj[e];
  float4 v = ((const float4*)x)[(size_t)s * 32 + q];
  float* o = out + (size_t)d * D + q * 4;
  atomicAdd(o + 0, v.x * a);
  atomicAdd(o + 1, v.y * a);
  atomicAdd(o + 2, v.z * a);
  atomicAdd(o + 3, v.w * a);
}

// tier-2/3 epilogue GEMM: out[r,:] = relu(out[r,:] @ W + y[r,:] + b)
__global__ __launch_bounds__(256) void gemm_fused_kernel(
    float* __restrict__ out, const float* __restrict__ w,
    const float* __restrict__ y, const float* __restrict__ bias, int nrows) {
  __shared__ float sW[D * D];
  __shared__ float sA[32 * D];
  const int tid = threadIdx.x;
  const int row0 = blockIdx.x * 32;

  const float4* w4 = (const float4*)w;
  float4* sW4 = (float4*)sW;
  for (int i = tid; i < D * D / 4; i += 256) sW4[i] = w4[i];

  const int nrow_blk = min(32, nrows - row0);
  const float4* out4_base = (const float4*)(out + (size_t)row0 * D);
  float4* sA4 = (float4*)sA;
  for (int i = tid; i < nrow_blk * 32; i += 256) sA4[i] = out4_base[i];
  __syncthreads();

  const int cg = tid & 31;
  const int rs = tid >> 5;

  float4 acc[4];
#pragma unroll
  for (int r = 0; r < 4; ++r) acc[r] = make_float4(0.f, 0.f, 0.f, 0.f);

#pragma unroll 4
  for (int k4 = 0; k4 < 32; ++k4) {
    float4 wv0 = sW4[(k4 * 4 + 0) * 32 + cg];
    float4 wv1 = sW4[(k4 * 4 + 1) * 32 + cg];
    float4 wv2 = sW4[(k4 * 4 + 2) * 32 + cg];
    float4 wv3 = sW4[(k4 * 4 + 3) * 32 + cg];
#pragma unroll
    for (int r = 0; r < 4; ++r) {
      float4 xv = sA4[(rs + r * 8) * 32 + k4];
      acc[r].x = fmaf(xv.x, wv0.x, acc[r].x);
      acc[r].y = fmaf(xv.x, wv0.y, acc[r].y);
      acc[r].z = fmaf(xv.x, wv0.z, acc[r].z);
      acc[r].w = fmaf(xv.x, wv0.w, acc[r].w);
      acc[r].x = fmaf(xv.y, wv1.x, acc[r].x);
      acc[r].y = fmaf(xv.y, wv1.y, acc[r].y);
      acc[r].z = fmaf(xv.y, wv1.z, acc[r].z);
      acc[r].w = fmaf(xv.y, wv1.w, acc[r].w);
      acc[r].x = fmaf(xv.z, wv2.x, acc[r].x);
      acc[r].y = fmaf(xv.z, wv2.y, acc[r].y);
      acc[r].z = fmaf(xv.z, wv2.z, acc[r].z);
      acc[r].w = fmaf(xv.z, wv2.w, acc[r].w);
      acc[r].x = fmaf(xv.w, wv3.x, acc[r].x);
      acc[r].y = fmaf(xv.w, wv3.y, acc[r].y);
      acc[r].z = fmaf(xv.w, wv3.z, acc[r].z);
      acc[r].w = fmaf(xv.w, wv3.w, acc[r].w);
    }
  }

  const float4* y4 = (const float4*)y;
  const float4* b4 = (const float4*)bias;
  float4* o4 = (float4*)out;
  float4 bv = b4[cg];
#pragma unroll
  for (int r = 0; r < 4; ++r) {
    int row = row0 + rs + r * 8;
    if (row < nrows) {
      float4 yv = y4[(size_t)row * 32 + cg];
      float4 res;
      res.x = fmaxf(acc[r].x + yv.x + bv.x, 0.f);
      res.y = fmaxf(acc[r].y + yv.y + bv.y, 0.f);
      res.z = fmaxf(acc[r].z + yv.z + bv.z, 0.f);
      res.w = fmaxf(acc[r].w + yv.w + bv.w, 0.f);
      o4[(size_t)row * 32 + cg] = res;
    }
  }
}

extern "C" void kernel_launch(void* const* d_in, const int* in_sizes, int n_in,
                              void* d_out, int out_size, void* d_ws, size_t ws_size,
                              hipStream_t stream) {
  const float* x    = (const float*)d_in[0];
  const float* y    = (const float*)d_in[1];
  const int*   esrc = (const int*)d_in[2];
  const int*   edst = (const int*)d_in[3];
  const float* adj  = (const float*)d_in[4];
  const float* w    = (const float*)d_in[5];
  const float* bias = (const float*)d_in[6];
  float* out = (float*)d_out;

  const int nNodes = in_sizes[0] / D;
  const int nE = in_sizes[2];
  const int n4 = nNodes * (D / 4);
  const int nB = (nNodes + 127) >> 7;
  const int nC = (nE + CE - 1) / CE;

  const size_t xb_bytes   = (size_t)nNodes * D * 2;
  const size_t edge_bytes = (size_t)nC * CE * 8;
  const size_t ofs_bytes  = ((size_t)nC * (nB + 1) * 2 + 3) & ~(size_t)3;
  const size_t need1 = xb_bytes + edge_bytes + ofs_bytes;

  const int nchunks = (nNodes + CHUNK - 1) / CHUNK;
  const size_t e2_bytes  = (size_t)nE * 8;
  const size_t int_bytes = (size_t)(3 * nNodes + 1 + 2 * nchunks) * 4;
  const size_t need2 = e2_bytes + int_bytes;

  if (ws_size >= need1 && nNodes <= 130944 && nC <= MAXC) {
    char* base = (char*)d_ws;
    ushort4* xb4 = (ushort4*)base;
    int2* edges = (int2*)(base + xb_bytes);
    unsigned short* ofs = (unsigned short*)(base + xb_bytes + edge_bytes);

    convert_kernel<<<(n4 + 255) / 256, 256, 0, stream>>>((const float4*)x, xb4, n4);
    chunk_sort_kernel<<<nC, 256, 0, stream>>>(esrc, edst, adj, edges, ofs, nE, nB);
    agg_gemm_kernel<<<nB, 512, 0, stream>>>((const unsigned*)xb4, edges, ofs, w, y,
                                            bias, out, nC, nB, nNodes);
  } else if (ws_size >= need2) {
    char* base = (char*)d_ws;
    int2* edges = (int2*)base;
    int* counts = (int*)(base + e2_bytes);
    int* row_start = counts + nNodes;
    int* cursor = row_start + nNodes + 1;
    int* chunk_sum = cursor + nNodes;
    int* chunk_off = chunk_sum + nchunks;

    zero_counts_kernel<<<(nNodes + 255) / 256, 256, 0, stream>>>(counts, nNodes);
    hist_kernel<<<(nE + 255) / 256, 256, 0, stream>>>(edst, counts, nE);
    scan_partial_kernel<<<nchunks, 256, 0, stream>>>(counts, chunk_sum, nNodes);
    scan_chunks_kernel<<<1, 64, 0, stream>>>(chunk_sum, chunk_off, row_start,
                                             nchunks, nNodes);
    scan_final_kernel<<<nchunks, 256, 0, stream>>>(counts, chunk_off, row_start,
                                                   cursor, nNodes);
    scatter_sort_kernel<<<(nE + 255) / 256, 256, 0, stream>>>(
        esrc, edst, adj, cursor, edges, nE);
    gather_fp32_kernel<<<(nNodes * 32 + 255) / 256, 256, 0, stream>>>(
        x, row_start, edges, out, nNodes);
    gemm_fused_kernel<<<(nNodes + 31) / 32, 256, 0, stream>>>(out, w, y, bias, nNodes);
  } else {
    zero_kernel<<<(n4 + 255) / 256, 256, 0, stream>>>((float4*)out, n4);
    scatter_atomic_kernel<<<((size_t)nE * 32 + 255) / 256, 256, 0, stream>>>(
        x, esrc, edst, adj, out, nE);
    gemm_fused_kernel<<<(nNodes + 31) / 32, 256, 0, stream>>>(out, w, y, bias, nNodes);
  }
}

// Round 6
// 433.770 us; speedup vs baseline: 3.5562x; 3.5562x over previous
//
#include <hip/hip_runtime.h>

#define D 128
#define CE 8192          // edges per sort chunk
#define NB_MAX 1024      // max buckets of 128 nodes -> nNodes <= 131072
#define MAXC 512         // max chunks (bucket_csr seg table)
#define CHUNK 1024       // tier-2 scan chunk

// out = relu( (sum_e a_e * x[src_e]) @ W + y + bias )   [linearity of GEMM]
// Round 6: chunk_sort (coalesced writes) -> bucket scan -> per-bucket CSR
// (XCD-local writes) -> proven bf16 gather -> fused GEMM epilogue.

__device__ __forceinline__ unsigned short f2bf(float f) {
  unsigned u = __float_as_uint(f);
  unsigned r = (u + 0x7fffu + ((u >> 16) & 1u)) >> 16;  // RNE
  return (unsigned short)r;
}

// ===================== x -> bf16 table =====================================
__global__ __launch_bounds__(256) void convert_kernel(
    const float4* __restrict__ x4, ushort4* __restrict__ xb4, int n4) {
  int i = blockIdx.x * 256 + threadIdx.x;
  if (i < n4) {
    float4 v = x4[i];
    ushort4 r;
    r.x = f2bf(v.x);
    r.y = f2bf(v.y);
    r.z = f2bf(v.z);
    r.w = f2bf(v.w);
    xb4[i] = r;
  }
}

// ===================== K2a: block-local counting sort (round-5 proven) =====
// Record: int2{ src | (dst&127)<<17 , bits(adj) }. Writes coalesced.
__global__ __launch_bounds__(256) void chunk_sort_kernel(
    const int* __restrict__ src, const int* __restrict__ dst,
    const float* __restrict__ adj, int2* __restrict__ edges,
    unsigned short* __restrict__ ofs, int nE, int nB) {
  __shared__ int2 stage[CE];       // 64 KB
  __shared__ int h[NB_MAX + 4];
  __shared__ int tsum[256];
  const int t = threadIdx.x;
  const int c = blockIdx.x;
  const int e0 = c * CE;
  const int n = min(CE, nE - e0);

  for (int i = t; i < NB_MAX + 4; i += 256) h[i] = 0;
  __syncthreads();

  for (int i = t; i < n; i += 256) atomicAdd(&h[dst[e0 + i] >> 7], 1);
  __syncthreads();

  const int base = t * 4;
  int v0 = h[base], v1 = h[base + 1], v2 = h[base + 2], v3 = h[base + 3];
  int s = v0 + v1 + v2 + v3;
  tsum[t] = s;
  __syncthreads();
  for (int off = 1; off < 256; off <<= 1) {
    int u = (t >= off) ? tsum[t - off] : 0;
    __syncthreads();
    tsum[t] += u;
    __syncthreads();
  }
  int excl = tsum[t] - s;
  h[base] = excl;
  h[base + 1] = excl + v0;
  h[base + 2] = excl + v0 + v1;
  h[base + 3] = excl + v0 + v1 + v2;
  __syncthreads();

  unsigned short* o = ofs + (size_t)c * (nB + 1);
  for (int i = t; i <= nB; i += 256) o[i] = (unsigned short)h[i];
  __syncthreads();

  for (int i = t; i < n; i += 256) {
    int e = e0 + i;
    int d = dst[e];
    int pos = atomicAdd(&h[d >> 7], 1);
    int2 ev;
    ev.x = src[e] | ((d & 127) << 17);
    ev.y = __float_as_int(adj[e]);
    stage[pos] = ev;
  }
  __syncthreads();

  for (int i = t; i < n; i += 256) edges[e0 + i] = stage[i];
}

// ===================== K2b: bucket totals + exclusive scan =================
__global__ __launch_bounds__(1024) void bucket_scan_kernel(
    const unsigned short* __restrict__ ofs, int* __restrict__ bases,
    int* __restrict__ row_start, int nC, int nB, int nE, int nNodes) {
  __shared__ int s[1024];
  const int t = threadIdx.x;
  int total = 0;
  if (t < nB) {
    for (int c = 0; c < nC; ++c) {
      const unsigned short* oc = ofs + (size_t)c * (nB + 1);
      total += (int)oc[t + 1] - (int)oc[t];
    }
  }
  s[t] = total;
  __syncthreads();
  for (int off = 1; off < 1024; off <<= 1) {
    int v = (t >= off) ? s[t - off] : 0;
    __syncthreads();
    s[t] += v;
    __syncthreads();
  }
  if (t < nB) bases[t] = s[t] - total;  // exclusive
  if (t == 0) {
    bases[nB] = nE;
    row_start[nNodes] = nE;
  }
}

// ===================== K2c: per-bucket node CSR (two-pass, XCD-local) ======
// Block b gathers its segments from all chunks, counting-sorts by node in
// LDS counters, writes node-grouped records to csr[bases[b]...] (one CU ->
// one XCD L2 -> no cross-XCD write amplification) and row_start[].
__global__ __launch_bounds__(256) void bucket_csr_kernel(
    const int2* __restrict__ tmp, const unsigned short* __restrict__ ofs,
    const int* __restrict__ bases, int2* __restrict__ csr,
    int* __restrict__ row_start, int nC, int nB, int nNodes) {
  __shared__ int segst[MAXC];
  __shared__ int segcnt[MAXC];
  __shared__ int cnt[128];
  __shared__ int cur[128];
  __shared__ int sc[128];
  const int t = threadIdx.x;
  const int b = blockIdx.x;

  for (int c = t; c < nC; c += 256) {
    int s0 = ofs[(size_t)c * (nB + 1) + b];
    int s1 = ofs[(size_t)c * (nB + 1) + b + 1];
    segst[c] = c * CE + s0;
    segcnt[c] = s1 - s0;
  }
  if (t < 128) cnt[t] = 0;
  __syncthreads();

  const int wv = t >> 6, l = t & 63;
  for (int c = wv; c < nC; c += 4) {
    int n = segcnt[c], st = segst[c];
    for (int i = l; i < n; i += 64) {
      int r = tmp[st + i].x;
      atomicAdd(&cnt[(r >> 17) & 127], 1);
    }
  }
  __syncthreads();

  if (t < 128) sc[t] = cnt[t];
  __syncthreads();
  for (int off = 1; off < 128; off <<= 1) {
    int v = 0;
    if (t < 128 && t >= off) v = sc[t - off];
    __syncthreads();
    if (t < 128) sc[t] += v;
    __syncthreads();
  }
  const int base = bases[b];
  if (t < 128) {
    int excl = sc[t] - cnt[t];
    cur[t] = excl;
    int node = (b << 7) + t;
    if (node < nNodes) row_start[node] = base + excl;
  }
  __syncthreads();

  for (int c = wv; c < nC; c += 4) {
    int n = segcnt[c], st = segst[c];
    for (int i = l; i < n; i += 64) {
      int2 e = tmp[st + i];
      int dl = (e.x >> 17) & 127;
      int pos = atomicAdd(&cur[dl], 1);
      int2 rec;
      rec.x = e.x & 0x1FFFF;
      rec.y = e.y;
      csr[(size_t)base + pos] = rec;
    }
  }
}

// ===================== Gather, bf16 table (round-4 proven) =================
__global__ __launch_bounds__(256) void gather_bf16_kernel(
    const uint2* __restrict__ xb, const int* __restrict__ row_start,
    const int2* __restrict__ edges, float* __restrict__ out, int nNodes) {
  int g = (blockIdx.x * 256 + threadIdx.x) >> 5;
  int q = threadIdx.x & 31;
  if (g >= nNodes) return;
  int beg = row_start[g], end = row_start[g + 1];
  float4 acc = make_float4(0.f, 0.f, 0.f, 0.f);
  int j = beg;
  for (; j + 1 < end; j += 2) {
    int2 e0 = edges[j], e1 = edges[j + 1];
    float a0 = __int_as_float(e0.y), a1 = __int_as_float(e1.y);
    uint2 v0 = xb[(size_t)e0.x * 32 + q];
    uint2 v1 = xb[(size_t)e1.x * 32 + q];
    acc.x = fmaf(a0, __uint_as_float(v0.x << 16), acc.x);
    acc.y = fmaf(a0, __uint_as_float(v0.x & 0xffff0000u), acc.y);
    acc.z = fmaf(a0, __uint_as_float(v0.y << 16), acc.z);
    acc.w = fmaf(a0, __uint_as_float(v0.y & 0xffff0000u), acc.w);
    acc.x = fmaf(a1, __uint_as_float(v1.x << 16), acc.x);
    acc.y = fmaf(a1, __uint_as_float(v1.x & 0xffff0000u), acc.y);
    acc.z = fmaf(a1, __uint_as_float(v1.y << 16), acc.z);
    acc.w = fmaf(a1, __uint_as_float(v1.y & 0xffff0000u), acc.w);
  }
  if (j < end) {
    int2 e0 = edges[j];
    float a0 = __int_as_float(e0.y);
    uint2 v0 = xb[(size_t)e0.x * 32 + q];
    acc.x = fmaf(a0, __uint_as_float(v0.x << 16), acc.x);
    acc.y = fmaf(a0, __uint_as_float(v0.x & 0xffff0000u), acc.y);
    acc.z = fmaf(a0, __uint_as_float(v0.y << 16), acc.z);
    acc.w = fmaf(a0, __uint_as_float(v0.y & 0xffff0000u), acc.w);
  }
  ((float4*)out)[(size_t)g * 32 + q] = acc;
}

// ======================= tier-2/3 fallbacks (proven) =======================
__global__ __launch_bounds__(256) void zero_counts_kernel(int* __restrict__ c, int n) {
  int i = blockIdx.x * 256 + threadIdx.x;
  if (i < n) c[i] = 0;
}

__global__ __launch_bounds__(256) void hist_kernel(
    const int* __restrict__ dst, int* __restrict__ counts, int nE) {
  int e = blockIdx.x * 256 + threadIdx.x;
  if (e < nE) atomicAdd(&counts[dst[e]], 1);
}

__global__ __launch_bounds__(256) void scan_partial_kernel(
    const int* __restrict__ counts, int* __restrict__ chunk_sum, int n) {
  __shared__ int sdata[256];
  int b = blockIdx.x, t = threadIdx.x;
  int base = b * CHUNK + t * 4;
  int s = 0;
#pragma unroll
  for (int k = 0; k < 4; ++k) {
    int i = base + k;
    if (i < n) s += counts[i];
  }
  sdata[t] = s;
  __syncthreads();
  for (int off = 128; off > 0; off >>= 1) {
    if (t < off) sdata[t] += sdata[t + off];
    __syncthreads();
  }
  if (t == 0) chunk_sum[b] = sdata[0];
}

__global__ void scan_chunks_kernel(const int* __restrict__ chunk_sum,
                                   int* __restrict__ chunk_off,
                                   int* __restrict__ row_start, int nchunks, int n) {
  if (threadIdx.x == 0 && blockIdx.x == 0) {
    int run = 0;
    for (int i = 0; i < nchunks; ++i) {
      chunk_off[i] = run;
      run += chunk_sum[i];
    }
    row_start[n] = run;
  }
}

__global__ __launch_bounds__(256) void scan_final_kernel(
    const int* __restrict__ counts, const int* __restrict__ chunk_off,
    int* __restrict__ row_start, int* __restrict__ cursor, int n) {
  __shared__ int sdata[256];
  int b = blockIdx.x, t = threadIdx.x;
  int base = b * CHUNK + t * 4;
  int c[4] = {0, 0, 0, 0};
#pragma unroll
  for (int k = 0; k < 4; ++k) {
    int i = base + k;
    if (i < n) c[k] = counts[i];
  }
  int tsum = c[0] + c[1] + c[2] + c[3];
  sdata[t] = tsum;
  __syncthreads();
  for (int off = 1; off < 256; off <<= 1) {
    int v = (t >= off) ? sdata[t - off] : 0;
    __syncthreads();
    sdata[t] += v;
    __syncthreads();
  }
  int run = sdata[t] - tsum + chunk_off[b];
#pragma unroll
  for (int k = 0; k < 4; ++k) {
    int i = base + k;
    if (i < n) {
      row_start[i] = run;
      cursor[i] = run;
      run += c[k];
    }
  }
}

__global__ __launch_bounds__(256) void scatter_sort_kernel(
    const int* __restrict__ src, const int* __restrict__ dst,
    const float* __restrict__ adj, int* __restrict__ cursor,
    int2* __restrict__ edges, int nE) {
  int e = blockIdx.x * 256 + threadIdx.x;
  if (e >= nE) return;
  int d = dst[e];
  int2 ev;
  ev.x = src[e];
  ev.y = __float_as_int(adj[e]);
  int pos = atomicAdd(&cursor[d], 1);
  edges[pos] = ev;
}

__global__ __launch_bounds__(256) void gather_fp32_kernel(
    const float* __restrict__ x, const int* __restrict__ row_start,
    const int2* __restrict__ edges, float* __restrict__ out, int nNodes) {
  int g = (blockIdx.x * 256 + threadIdx.x) >> 5;
  int q = threadIdx.x & 31;
  if (g >= nNodes) return;
  int beg = row_start[g], end = row_start[g + 1];
  const float4* x4 = (const float4*)x;
  float4 acc = make_float4(0.f, 0.f, 0.f, 0.f);
  for (int j = beg; j < end; ++j) {
    int2 e0 = edges[j];
    float a0 = __int_as_float(e0.y);
    float4 v0 = x4[(size_t)e0.x * 32 + q];
    acc.x = fmaf(a0, v0.x, acc.x);
    acc.y = fmaf(a0, v0.y, acc.y);
    acc.z = fmaf(a0, v0.z, acc.z);
    acc.w = fmaf(a0, v0.w, acc.w);
  }
  ((float4*)out)[(size_t)g * 32 + q] = acc;
}

__global__ __launch_bounds__(256) void zero_kernel(float4* __restrict__ out, int n4) {
  int i = blockIdx.x * 256 + threadIdx.x;
  if (i < n4) out[i] = make_float4(0.f, 0.f, 0.f, 0.f);
}

__global__ __launch_bounds__(256) void scatter_atomic_kernel(
    const float* __restrict__ x, const int* __restrict__ src,
    const int* __restrict__ dst, const float* __restrict__ adj,
    float* __restrict__ out, int nE) {
  int tid = blockIdx.x * 256 + threadIdx.x;
  int e = tid >> 5;
  int q = tid & 31;
  if (e >= nE) return;
  int s = src[e];
  int d = dst[e];
  float a = adj[e];
  float4 v = ((const float4*)x)[(size_t)s * 32 + q];
  float* o = out + (size_t)d * D + q * 4;
  atomicAdd(o + 0, v.x * a);
  atomicAdd(o + 1, v.y * a);
  atomicAdd(o + 2, v.z * a);
  atomicAdd(o + 3, v.w * a);
}

// ===================== Fused GEMM epilogue (proven) ========================
__global__ __launch_bounds__(256) void gemm_fused_kernel(
    float* __restrict__ out, const float* __restrict__ w,
    const float* __restrict__ y, const float* __restrict__ bias, int nrows) {
  __shared__ float sW[D * D];
  __shared__ float sA[32 * D];
  const int tid = threadIdx.x;
  const int row0 = blockIdx.x * 32;

  const float4* w4 = (const float4*)w;
  float4* sW4 = (float4*)sW;
  for (int i = tid; i < D * D / 4; i += 256) sW4[i] = w4[i];

  const int nrow_blk = min(32, nrows - row0);
  const float4* out4_base = (const float4*)(out + (size_t)row0 * D);
  float4* sA4 = (float4*)sA;
  for (int i = tid; i < nrow_blk * 32; i += 256) sA4[i] = out4_base[i];
  __syncthreads();

  const int cg = tid & 31;
  const int rs = tid >> 5;

  float4 acc[4];
#pragma unroll
  for (int r = 0; r < 4; ++r) acc[r] = make_float4(0.f, 0.f, 0.f, 0.f);

#pragma unroll 4
  for (int k4 = 0; k4 < 32; ++k4) {
    float4 wv0 = sW4[(k4 * 4 + 0) * 32 + cg];
    float4 wv1 = sW4[(k4 * 4 + 1) * 32 + cg];
    float4 wv2 = sW4[(k4 * 4 + 2) * 32 + cg];
    float4 wv3 = sW4[(k4 * 4 + 3) * 32 + cg];
#pragma unroll
    for (int r = 0; r < 4; ++r) {
      float4 xv = sA4[(rs + r * 8) * 32 + k4];
      acc[r].x = fmaf(xv.x, wv0.x, acc[r].x);
      acc[r].y = fmaf(xv.x, wv0.y, acc[r].y);
      acc[r].z = fmaf(xv.x, wv0.z, acc[r].z);
      acc[r].w = fmaf(xv.x, wv0.w, acc[r].w);
      acc[r].x = fmaf(xv.y, wv1.x, acc[r].x);
      acc[r].y = fmaf(xv.y, wv1.y, acc[r].y);
      acc[r].z = fmaf(xv.y, wv1.z, acc[r].z);
      acc[r].w = fmaf(xv.y, wv1.w, acc[r].w);
      acc[r].x = fmaf(xv.z, wv2.x, acc[r].x);
      acc[r].y = fmaf(xv.z, wv2.y, acc[r].y);
      acc[r].z = fmaf(xv.z, wv2.z, acc[r].z);
      acc[r].w = fmaf(xv.z, wv2.w, acc[r].w);
      acc[r].x = fmaf(xv.w, wv3.x, acc[r].x);
      acc[r].y = fmaf(xv.w, wv3.y, acc[r].y);
      acc[r].z = fmaf(xv.w, wv3.z, acc[r].z);
      acc[r].w = fmaf(xv.w, wv3.w, acc[r].w);
    }
  }

  const float4* y4 = (const float4*)y;
  const float4* b4 = (const float4*)bias;
  float4* o4 = (float4*)out;
  float4 bv = b4[cg];
#pragma unroll
  for (int r = 0; r < 4; ++r) {
    int row = row0 + rs + r * 8;
    if (row < nrows) {
      float4 yv = y4[(size_t)row * 32 + cg];
      float4 res;
      res.x = fmaxf(acc[r].x + yv.x + bv.x, 0.f);
      res.y = fmaxf(acc[r].y + yv.y + bv.y, 0.f);
      res.z = fmaxf(acc[r].z + yv.z + bv.z, 0.f);
      res.w = fmaxf(acc[r].w + yv.w + bv.w, 0.f);
      o4[(size_t)row * 32 + cg] = res;
    }
  }
}

extern "C" void kernel_launch(void* const* d_in, const int* in_sizes, int n_in,
                              void* d_out, int out_size, void* d_ws, size_t ws_size,
                              hipStream_t stream) {
  const float* x    = (const float*)d_in[0];
  const float* y    = (const float*)d_in[1];
  const int*   esrc = (const int*)d_in[2];
  const int*   edst = (const int*)d_in[3];
  const float* adj  = (const float*)d_in[4];
  const float* w    = (const float*)d_in[5];
  const float* bias = (const float*)d_in[6];
  float* out = (float*)d_out;

  const int nNodes = in_sizes[0] / D;
  const int nE = in_sizes[2];
  const int n4 = nNodes * (D / 4);
  const int nB = (nNodes + 127) >> 7;
  const int nC = (nE + CE - 1) / CE;

  // tier-1 workspace: [csr | row_start | ofs | bases | overlay(tmp->xb)]
  const size_t csr_bytes  = (size_t)nE * 8;
  const size_t rs_bytes   = (size_t)(nNodes + 1) * 4;
  const size_t ofs_bytes  = (((size_t)nC * (nB + 1) * 2) + 3) & ~(size_t)3;
  const size_t base_bytes = (size_t)(nB + 1) * 4;
  const size_t tmp_bytes  = (size_t)nC * CE * 8;
  const size_t xb_bytes   = (size_t)nNodes * D * 2;
  const size_t ovl_bytes  = tmp_bytes > xb_bytes ? tmp_bytes : xb_bytes;
  const size_t need1 = csr_bytes + rs_bytes + ofs_bytes + base_bytes + ovl_bytes;

  const int nchunks = (nNodes + CHUNK - 1) / CHUNK;
  const size_t e2_bytes  = (size_t)nE * 8;
  const size_t int_bytes = (size_t)(3 * nNodes + 1 + 2 * nchunks) * 4;
  const size_t need2 = e2_bytes + int_bytes;

  if (ws_size >= need1 && nNodes <= NB_MAX * 128 && nC <= MAXC) {
    char* p = (char*)d_ws;
    int2* csr = (int2*)p;                       p += csr_bytes;
    int* row_start = (int*)p;                   p += rs_bytes;
    unsigned short* ofs = (unsigned short*)p;   p += ofs_bytes;
    int* bases = (int*)p;                       p += base_bytes;
    int2* tmp = (int2*)p;           // overlay: edges during CSR build,
    ushort4* xb4 = (ushort4*)p;     // then bf16 x-table for gather

    chunk_sort_kernel<<<nC, 256, 0, stream>>>(esrc, edst, adj, tmp, ofs, nE, nB);
    bucket_scan_kernel<<<1, 1024, 0, stream>>>(ofs, bases, row_start, nC, nB,
                                               nE, nNodes);
    bucket_csr_kernel<<<nB, 256, 0, stream>>>(tmp, ofs, bases, csr, row_start,
                                              nC, nB, nNodes);
    convert_kernel<<<(n4 + 255) / 256, 256, 0, stream>>>((const float4*)x, xb4, n4);
    gather_bf16_kernel<<<(nNodes * 32 + 255) / 256, 256, 0, stream>>>(
        (const uint2*)xb4, row_start, csr, out, nNodes);
    gemm_fused_kernel<<<(nNodes + 31) / 32, 256, 0, stream>>>(out, w, y, bias,
                                                              nNodes);
  } else if (ws_size >= need2) {
    char* base = (char*)d_ws;
    int2* edges = (int2*)base;
    int* counts = (int*)(base + e2_bytes);
    int* row_start = counts + nNodes;
    int* cursor = row_start + nNodes + 1;
    int* chunk_sum = cursor + nNodes;
    int* chunk_off = chunk_sum + nchunks;

    zero_counts_kernel<<<(nNodes + 255) / 256, 256, 0, stream>>>(counts, nNodes);
    hist_kernel<<<(nE + 255) / 256, 256, 0, stream>>>(edst, counts, nE);
    scan_partial_kernel<<<nchunks, 256, 0, stream>>>(counts, chunk_sum, nNodes);
    scan_chunks_kernel<<<1, 64, 0, stream>>>(chunk_sum, chunk_off, row_start,
                                             nchunks, nNodes);
    scan_final_kernel<<<nchunks, 256, 0, stream>>>(counts, chunk_off, row_start,
                                                   cursor, nNodes);
    scatter_sort_kernel<<<(nE + 255) / 256, 256, 0, stream>>>(
        esrc, edst, adj, cursor, edges, nE);
    gather_fp32_kernel<<<(nNodes * 32 + 255) / 256, 256, 0, stream>>>(
        x, row_start, edges, out, nNodes);
    gemm_fused_kernel<<<(nNodes + 31) / 32, 256, 0, stream>>>(out, w, y, bias,
                                                              nNodes);
  } else {
    zero_kernel<<<(n4 + 255) / 256, 256, 0, stream>>>((float4*)out, n4);
    scatter_atomic_kernel<<<((size_t)nE * 32 + 255) / 256, 256, 0, stream>>>(
        x, esrc, edst, adj, out, nE);
    gemm_fused_kernel<<<(nNodes + 31) / 32, 256, 0, stream>>>(out, w, y, bias,
                                                              nNodes);
  }
}

// Round 7
// 417.486 us; speedup vs baseline: 3.6949x; 1.0390x over previous
//
#include <hip/hip_runtime.h>

#define D 128
#define CE 8192          // edges per sort chunk
#define NB_MAX 1024      // max buckets of 128 nodes -> nNodes <= 131072
#define MAXC 512         // max chunks (bucket_csr seg table)
#define CHUNK 1024       // tier-2 scan chunk
#define WTP 136          // Wt row pitch in ushorts (pad breaks LDS bank pattern)

// out = relu( (sum_e a_e * x[src_e]) @ W + y + bias )   [linearity of GEMM]
// Round 7: gather packs bf16 agg into d_out (512B pitch), MFMA bf16 GEMM.

typedef __attribute__((ext_vector_type(8))) short bf16x8;
typedef __attribute__((ext_vector_type(4))) float f32x4;

__device__ __forceinline__ unsigned short f2bf(float f) {
  unsigned u = __float_as_uint(f);
  unsigned r = (u + 0x7fffu + ((u >> 16) & 1u)) >> 16;  // RNE
  return (unsigned short)r;
}

// ===================== x -> bf16 table =====================================
__global__ __launch_bounds__(256) void convert_kernel(
    const float4* __restrict__ x4, ushort4* __restrict__ xb4, int n4) {
  int i = blockIdx.x * 256 + threadIdx.x;
  if (i < n4) {
    float4 v = x4[i];
    ushort4 r;
    r.x = f2bf(v.x);
    r.y = f2bf(v.y);
    r.z = f2bf(v.z);
    r.w = f2bf(v.w);
    xb4[i] = r;
  }
}

// ===================== W -> transposed bf16 Wt[n][k] =======================
__global__ __launch_bounds__(256) void wt_convert_kernel(
    const float* __restrict__ w, unsigned short* __restrict__ wt) {
  int idx = blockIdx.x * 256 + threadIdx.x;  // 16384 threads
  int n = idx >> 7, k = idx & 127;
  wt[n * WTP + k] = f2bf(w[k * D + n]);
}

// ===================== K2a: block-local counting sort ======================
// Record: int2{ src | (dst&127)<<17 , bits(adj) }. Writes coalesced.
__global__ __launch_bounds__(256) void chunk_sort_kernel(
    const int* __restrict__ src, const int* __restrict__ dst,
    const float* __restrict__ adj, int2* __restrict__ edges,
    unsigned short* __restrict__ ofs, int nE, int nB) {
  __shared__ int2 stage[CE];       // 64 KB
  __shared__ int h[NB_MAX + 4];
  __shared__ int tsum[256];
  const int t = threadIdx.x;
  const int c = blockIdx.x;
  const int e0 = c * CE;
  const int n = min(CE, nE - e0);

  for (int i = t; i < NB_MAX + 4; i += 256) h[i] = 0;
  __syncthreads();

  for (int i = t; i < n; i += 256) atomicAdd(&h[dst[e0 + i] >> 7], 1);
  __syncthreads();

  const int base = t * 4;
  int v0 = h[base], v1 = h[base + 1], v2 = h[base + 2], v3 = h[base + 3];
  int s = v0 + v1 + v2 + v3;
  tsum[t] = s;
  __syncthreads();
  for (int off = 1; off < 256; off <<= 1) {
    int u = (t >= off) ? tsum[t - off] : 0;
    __syncthreads();
    tsum[t] += u;
    __syncthreads();
  }
  int excl = tsum[t] - s;
  h[base] = excl;
  h[base + 1] = excl + v0;
  h[base + 2] = excl + v0 + v1;
  h[base + 3] = excl + v0 + v1 + v2;
  __syncthreads();

  unsigned short* o = ofs + (size_t)c * (nB + 1);
  for (int i = t; i <= nB; i += 256) o[i] = (unsigned short)h[i];
  __syncthreads();

  for (int i = t; i < n; i += 256) {
    int e = e0 + i;
    int d = dst[e];
    int pos = atomicAdd(&h[d >> 7], 1);
    int2 ev;
    ev.x = src[e] | ((d & 127) << 17);
    ev.y = __float_as_int(adj[e]);
    stage[pos] = ev;
  }
  __syncthreads();

  for (int i = t; i < n; i += 256) edges[e0 + i] = stage[i];
}

// ===================== K2b: bucket totals + exclusive scan =================
__global__ __launch_bounds__(1024) void bucket_scan_kernel(
    const unsigned short* __restrict__ ofs, int* __restrict__ bases,
    int* __restrict__ row_start, int nC, int nB, int nE, int nNodes) {
  __shared__ int s[1024];
  const int t = threadIdx.x;
  int total = 0;
  if (t < nB) {
    for (int c = 0; c < nC; ++c) {
      const unsigned short* oc = ofs + (size_t)c * (nB + 1);
      total += (int)oc[t + 1] - (int)oc[t];
    }
  }
  s[t] = total;
  __syncthreads();
  for (int off = 1; off < 1024; off <<= 1) {
    int v = (t >= off) ? s[t - off] : 0;
    __syncthreads();
    s[t] += v;
    __syncthreads();
  }
  if (t < nB) bases[t] = s[t] - total;  // exclusive
  if (t == 0) {
    bases[nB] = nE;
    row_start[nNodes] = nE;
  }
}

// ===================== K2c: per-bucket node CSR (two-pass, XCD-local) ======
__global__ __launch_bounds__(256) void bucket_csr_kernel(
    const int2* __restrict__ tmp, const unsigned short* __restrict__ ofs,
    const int* __restrict__ bases, int2* __restrict__ csr,
    int* __restrict__ row_start, int nC, int nB, int nNodes) {
  __shared__ int segst[MAXC];
  __shared__ int segcnt[MAXC];
  __shared__ int cnt[128];
  __shared__ int cur[128];
  __shared__ int sc[128];
  const int t = threadIdx.x;
  const int b = blockIdx.x;

  for (int c = t; c < nC; c += 256) {
    int s0 = ofs[(size_t)c * (nB + 1) + b];
    int s1 = ofs[(size_t)c * (nB + 1) + b + 1];
    segst[c] = c * CE + s0;
    segcnt[c] = s1 - s0;
  }
  if (t < 128) cnt[t] = 0;
  __syncthreads();

  const int wv = t >> 6, l = t & 63;
  for (int c = wv; c < nC; c += 4) {
    int n = segcnt[c], st = segst[c];
    for (int i = l; i < n; i += 64) {
      int r = tmp[st + i].x;
      atomicAdd(&cnt[(r >> 17) & 127], 1);
    }
  }
  __syncthreads();

  if (t < 128) sc[t] = cnt[t];
  __syncthreads();
  for (int off = 1; off < 128; off <<= 1) {
    int v = 0;
    if (t < 128 && t >= off) v = sc[t - off];
    __syncthreads();
    if (t < 128) sc[t] += v;
    __syncthreads();
  }
  const int base = bases[b];
  if (t < 128) {
    int excl = sc[t] - cnt[t];
    cur[t] = excl;
    int node = (b << 7) + t;
    if (node < nNodes) row_start[node] = base + excl;
  }
  __syncthreads();

  for (int c = wv; c < nC; c += 4) {
    int n = segcnt[c], st = segst[c];
    for (int i = l; i < n; i += 64) {
      int2 e = tmp[st + i];
      int dl = (e.x >> 17) & 127;
      int pos = atomicAdd(&cur[dl], 1);
      int2 rec;
      rec.x = e.x & 0x1FFFF;
      rec.y = e.y;
      csr[(size_t)base + pos] = rec;
    }
  }
}

// ========== Gather -> packed bf16 agg rows inside d_out (512B pitch) =======
__global__ __launch_bounds__(256) void gather_pack_kernel(
    const uint2* __restrict__ xb, const int* __restrict__ row_start,
    const int2* __restrict__ edges, char* out, int nNodes) {
  int g = (blockIdx.x * 256 + threadIdx.x) >> 5;
  int q = threadIdx.x & 31;
  if (g >= nNodes) return;
  int beg = row_start[g], end = row_start[g + 1];
  float4 acc = make_float4(0.f, 0.f, 0.f, 0.f);
  int j = beg;
  for (; j + 1 < end; j += 2) {
    int2 e0 = edges[j], e1 = edges[j + 1];
    float a0 = __int_as_float(e0.y), a1 = __int_as_float(e1.y);
    uint2 v0 = xb[(size_t)e0.x * 32 + q];
    uint2 v1 = xb[(size_t)e1.x * 32 + q];
    acc.x = fmaf(a0, __uint_as_float(v0.x << 16), acc.x);
    acc.y = fmaf(a0, __uint_as_float(v0.x & 0xffff0000u), acc.y);
    acc.z = fmaf(a0, __uint_as_float(v0.y << 16), acc.z);
    acc.w = fmaf(a0, __uint_as_float(v0.y & 0xffff0000u), acc.w);
    acc.x = fmaf(a1, __uint_as_float(v1.x << 16), acc.x);
    acc.y = fmaf(a1, __uint_as_float(v1.x & 0xffff0000u), acc.y);
    acc.z = fmaf(a1, __uint_as_float(v1.y << 16), acc.z);
    acc.w = fmaf(a1, __uint_as_float(v1.y & 0xffff0000u), acc.w);
  }
  if (j < end) {
    int2 e0 = edges[j];
    float a0 = __int_as_float(e0.y);
    uint2 v0 = xb[(size_t)e0.x * 32 + q];
    acc.x = fmaf(a0, __uint_as_float(v0.x << 16), acc.x);
    acc.y = fmaf(a0, __uint_as_float(v0.x & 0xffff0000u), acc.y);
    acc.z = fmaf(a0, __uint_as_float(v0.y << 16), acc.z);
    acc.w = fmaf(a0, __uint_as_float(v0.y & 0xffff0000u), acc.w);
  }
  uint2 pk;
  pk.x = (unsigned)f2bf(acc.x) | ((unsigned)f2bf(acc.y) << 16);
  pk.y = (unsigned)f2bf(acc.z) | ((unsigned)f2bf(acc.w) << 16);
  ((uint2*)(out + (size_t)g * 512))[q] = pk;
}

// ===================== MFMA GEMM + epilogue ================================
// Block: 4 waves x 32 rows = 128 rows. Wave w: rows row0..row0+31 (two 16-row
// subtiles). A-frag: agg bf16 row at 512B pitch, lane m=l&15, k=quad*8..+8
// (16B contiguous, line-exact). B-frag: Wt[n][k] in LDS. C/D: col=l&15,
// row=quad*4+reg [m89]. Each wave reads & writes only its own 32 rows ->
// in-place over d_out is hazard-free.
__global__ __launch_bounds__(256) void gemm_mfma_kernel(
    const char* aggb, const unsigned short* __restrict__ wt,
    const float* __restrict__ y, const float* __restrict__ bias,
    float* out, int nNodes) {
  __shared__ unsigned short sWt[D * WTP];  // 34 KB
  const int t = threadIdx.x;
  for (int i = t; i < D * WTP / 8; i += 256)
    ((int4*)sWt)[i] = ((const int4*)wt)[i];
  __syncthreads();

  const int w = t >> 6, l = t & 63;
  const int quad = l >> 4, m = l & 15;
  const int row0 = blockIdx.x * 128 + w * 32;

  const int ar0 = min(row0 + m, nNodes - 1);
  const int ar1 = min(row0 + 16 + m, nNodes - 1);
  const char* pa0 = aggb + (size_t)ar0 * 512;
  const char* pa1 = aggb + (size_t)ar1 * 512;

  f32x4 acc0[8], acc1[8];
#pragma unroll
  for (int nt = 0; nt < 8; ++nt) {
    acc0[nt] = (f32x4){0.f, 0.f, 0.f, 0.f};
    acc1[nt] = (f32x4){0.f, 0.f, 0.f, 0.f};
  }

#pragma unroll
  for (int ks = 0; ks < 4; ++ks) {
    const int kof = ks * 32 + quad * 8;
    bf16x8 a0 = *(const bf16x8*)(pa0 + kof * 2);
    bf16x8 a1 = *(const bf16x8*)(pa1 + kof * 2);
#pragma unroll
    for (int nt = 0; nt < 8; ++nt) {
      bf16x8 b = *(const bf16x8*)&sWt[(nt * 16 + m) * WTP + kof];
      acc0[nt] = __builtin_amdgcn_mfma_f32_16x16x32_bf16(a0, b, acc0[nt], 0, 0, 0);
      acc1[nt] = __builtin_amdgcn_mfma_f32_16x16x32_bf16(a1, b, acc1[nt], 0, 0, 0);
    }
  }

  float bv[8];
#pragma unroll
  for (int nt = 0; nt < 8; ++nt) bv[nt] = bias[nt * 16 + m];

#pragma unroll
  for (int s = 0; s < 2; ++s) {
#pragma unroll
    for (int r = 0; r < 4; ++r) {
      int row = row0 + s * 16 + quad * 4 + r;
      if (row >= nNodes) continue;
      const float* yr = y + (size_t)row * D;
      float* orow = out + (size_t)row * D;
#pragma unroll
      for (int nt = 0; nt < 8; ++nt) {
        int c = nt * 16 + m;
        float v = (s == 0 ? acc0[nt][r] : acc1[nt][r]) + yr[c] + bv[nt];
        orow[c] = fmaxf(v, 0.f);
      }
    }
  }
}

// ======================= tier-2/3 fallbacks (proven) =======================
__global__ __launch_bounds__(256) void zero_counts_kernel(int* __restrict__ c, int n) {
  int i = blockIdx.x * 256 + threadIdx.x;
  if (i < n) c[i] = 0;
}

__global__ __launch_bounds__(256) void hist_kernel(
    const int* __restrict__ dst, int* __restrict__ counts, int nE) {
  int e = blockIdx.x * 256 + threadIdx.x;
  if (e < nE) atomicAdd(&counts[dst[e]], 1);
}

__global__ __launch_bounds__(256) void scan_partial_kernel(
    const int* __restrict__ counts, int* __restrict__ chunk_sum, int n) {
  __shared__ int sdata[256];
  int b = blockIdx.x, t = threadIdx.x;
  int base = b * CHUNK + t * 4;
  int s = 0;
#pragma unroll
  for (int k = 0; k < 4; ++k) {
    int i = base + k;
    if (i < n) s += counts[i];
  }
  sdata[t] = s;
  __syncthreads();
  for (int off = 128; off > 0; off >>= 1) {
    if (t < off) sdata[t] += sdata[t + off];
    __syncthreads();
  }
  if (t == 0) chunk_sum[b] = sdata[0];
}

__global__ void scan_chunks_kernel(const int* __restrict__ chunk_sum,
                                   int* __restrict__ chunk_off,
                                   int* __restrict__ row_start, int nchunks, int n) {
  if (threadIdx.x == 0 && blockIdx.x == 0) {
    int run = 0;
    for (int i = 0; i < nchunks; ++i) {
      chunk_off[i] = run;
      run += chunk_sum[i];
    }
    row_start[n] = run;
  }
}

__global__ __launch_bounds__(256) void scan_final_kernel(
    const int* __restrict__ counts, const int* __restrict__ chunk_off,
    int* __restrict__ row_start, int* __restrict__ cursor, int n) {
  __shared__ int sdata[256];
  int b = blockIdx.x, t = threadIdx.x;
  int base = b * CHUNK + t * 4;
  int c[4] = {0, 0, 0, 0};
#pragma unroll
  for (int k = 0; k < 4; ++k) {
    int i = base + k;
    if (i < n) c[k] = counts[i];
  }
  int tsum = c[0] + c[1] + c[2] + c[3];
  sdata[t] = tsum;
  __syncthreads();
  for (int off = 1; off < 256; off <<= 1) {
    int v = (t >= off) ? sdata[t - off] : 0;
    __syncthreads();
    sdata[t] += v;
    __syncthreads();
  }
  int run = sdata[t] - tsum + chunk_off[b];
#pragma unroll
  for (int k = 0; k < 4; ++k) {
    int i = base + k;
    if (i < n) {
      row_start[i] = run;
      cursor[i] = run;
      run += c[k];
    }
  }
}

__global__ __launch_bounds__(256) void scatter_sort_kernel(
    const int* __restrict__ src, const int* __restrict__ dst,
    const float* __restrict__ adj, int* __restrict__ cursor,
    int2* __restrict__ edges, int nE) {
  int e = blockIdx.x * 256 + threadIdx.x;
  if (e >= nE) return;
  int d = dst[e];
  int2 ev;
  ev.x = src[e];
  ev.y = __float_as_int(adj[e]);
  int pos = atomicAdd(&cursor[d], 1);
  edges[pos] = ev;
}

__global__ __launch_bounds__(256) void gather_fp32_kernel(
    const float* __restrict__ x, const int* __restrict__ row_start,
    const int2* __restrict__ edges, float* __restrict__ out, int nNodes) {
  int g = (blockIdx.x * 256 + threadIdx.x) >> 5;
  int q = threadIdx.x & 31;
  if (g >= nNodes) return;
  int beg = row_start[g], end = row_start[g + 1];
  const float4* x4 = (const float4*)x;
  float4 acc = make_float4(0.f, 0.f, 0.f, 0.f);
  for (int j = beg; j < end; ++j) {
    int2 e0 = edges[j];
    float a0 = __int_as_float(e0.y);
    float4 v0 = x4[(size_t)e0.x * 32 + q];
    acc.x = fmaf(a0, v0.x, acc.x);
    acc.y = fmaf(a0, v0.y, acc.y);
    acc.z = fmaf(a0, v0.z, acc.z);
    acc.w = fmaf(a0, v0.w, acc.w);
  }
  ((float4*)out)[(size_t)g * 32 + q] = acc;
}

__global__ __launch_bounds__(256) void zero_kernel(float4* __restrict__ out, int n4) {
  int i = blockIdx.x * 256 + threadIdx.x;
  if (i < n4) out[i] = make_float4(0.f, 0.f, 0.f, 0.f);
}

__global__ __launch_bounds__(256) void scatter_atomic_kernel(
    const float* __restrict__ x, const int* __restrict__ src,
    const int* __restrict__ dst, const float* __restrict__ adj,
    float* __restrict__ out, int nE) {
  int tid = blockIdx.x * 256 + threadIdx.x;
  int e = tid >> 5;
  int q = tid & 31;
  if (e >= nE) return;
  int s = src[e];
  int d = dst[e];
  float a = adj[e];
  float4 v = ((const float4*)x)[(size_t)s * 32 + q];
  float* o = out + (size_t)d * D + q * 4;
  atomicAdd(o + 0, v.x * a);
  atomicAdd(o + 1, v.y * a);
  atomicAdd(o + 2, v.z * a);
  atomicAdd(o + 3, v.w * a);
}

// tier-2/3 epilogue GEMM (fp32 in-place)
__global__ __launch_bounds__(256) void gemm_fused_kernel(
    float* __restrict__ out, const float* __restrict__ w,
    const float* __restrict__ y, const float* __restrict__ bias, int nrows) {
  __shared__ float sW[D * D];
  __shared__ float sA[32 * D];
  const int tid = threadIdx.x;
  const int row0 = blockIdx.x * 32;

  const float4* w4 = (const float4*)w;
  float4* sW4 = (float4*)sW;
  for (int i = tid; i < D * D / 4; i += 256) sW4[i] = w4[i];

  const int nrow_blk = min(32, nrows - row0);
  const float4* out4_base = (const float4*)(out + (size_t)row0 * D);
  float4* sA4 = (float4*)sA;
  for (int i = tid; i < nrow_blk * 32; i += 256) sA4[i] = out4_base[i];
  __syncthreads();

  const int cg = tid & 31;
  const int rs = tid >> 5;

  float4 acc[4];
#pragma unroll
  for (int r = 0; r < 4; ++r) acc[r] = make_float4(0.f, 0.f, 0.f, 0.f);

#pragma unroll 4
  for (int k4 = 0; k4 < 32; ++k4) {
    float4 wv0 = sW4[(k4 * 4 + 0) * 32 + cg];
    float4 wv1 = sW4[(k4 * 4 + 1) * 32 + cg];
    float4 wv2 = sW4[(k4 * 4 + 2) * 32 + cg];
    float4 wv3 = sW4[(k4 * 4 + 3) * 32 + cg];
#pragma unroll
    for (int r = 0; r < 4; ++r) {
      float4 xv = sA4[(rs + r * 8) * 32 + k4];
      acc[r].x = fmaf(xv.x, wv0.x, acc[r].x);
      acc[r].y = fmaf(xv.x, wv0.y, acc[r].y);
      acc[r].z = fmaf(xv.x, wv0.z, acc[r].z);
      acc[r].w = fmaf(xv.x, wv0.w, acc[r].w);
      acc[r].x = fmaf(xv.y, wv1.x, acc[r].x);
      acc[r].y = fmaf(xv.y, wv1.y, acc[r].y);
      acc[r].z = fmaf(xv.y, wv1.z, acc[r].z);
      acc[r].w = fmaf(xv.y, wv1.w, acc[r].w);
      acc[r].x = fmaf(xv.z, wv2.x, acc[r].x);
      acc[r].y = fmaf(xv.z, wv2.y, acc[r].y);
      acc[r].z = fmaf(xv.z, wv2.z, acc[r].z);
      acc[r].w = fmaf(xv.z, wv2.w, acc[r].w);
      acc[r].x = fmaf(xv.w, wv3.x, acc[r].x);
      acc[r].y = fmaf(xv.w, wv3.y, acc[r].y);
      acc[r].z = fmaf(xv.w, wv3.z, acc[r].z);
      acc[r].w = fmaf(xv.w, wv3.w, acc[r].w);
    }
  }

  const float4* y4 = (const float4*)y;
  const float4* b4 = (const float4*)bias;
  float4* o4 = (float4*)out;
  float4 bv = b4[cg];
#pragma unroll
  for (int r = 0; r < 4; ++r) {
    int row = row0 + rs + r * 8;
    if (row < nrows) {
      float4 yv = y4[(size_t)row * 32 + cg];
      float4 res;
      res.x = fmaxf(acc[r].x + yv.x + bv.x, 0.f);
      res.y = fmaxf(acc[r].y + yv.y + bv.y, 0.f);
      res.z = fmaxf(acc[r].z + yv.z + bv.z, 0.f);
      res.w = fmaxf(acc[r].w + yv.w + bv.w, 0.f);
      o4[(size_t)row * 32 + cg] = res;
    }
  }
}

extern "C" void kernel_launch(void* const* d_in, const int* in_sizes, int n_in,
                              void* d_out, int out_size, void* d_ws, size_t ws_size,
                              hipStream_t stream) {
  const float* x    = (const float*)d_in[0];
  const float* y    = (const float*)d_in[1];
  const int*   esrc = (const int*)d_in[2];
  const int*   edst = (const int*)d_in[3];
  const float* adj  = (const float*)d_in[4];
  const float* w    = (const float*)d_in[5];
  const float* bias = (const float*)d_in[6];
  float* out = (float*)d_out;

  const int nNodes = in_sizes[0] / D;
  const int nE = in_sizes[2];
  const int n4 = nNodes * (D / 4);
  const int nB = (nNodes + 127) >> 7;
  const int nC = (nE + CE - 1) / CE;

  // tier-1 workspace: [csr | row_start | ofs | bases | wt | overlay(tmp->xb)]
  const size_t csr_bytes  = (size_t)nE * 8;
  const size_t rs_bytes   = (size_t)(nNodes + 1) * 4;
  const size_t ofs_bytes  = (((size_t)nC * (nB + 1) * 2) + 15) & ~(size_t)15;
  const size_t base_bytes = (((size_t)(nB + 1) * 4) + 15) & ~(size_t)15;
  const size_t wt_bytes   = (size_t)D * WTP * 2;  // 34816, 16B-aligned
  const size_t tmp_bytes  = (size_t)nC * CE * 8;
  const size_t xb_bytes   = (size_t)nNodes * D * 2;
  const size_t ovl_bytes  = tmp_bytes > xb_bytes ? tmp_bytes : xb_bytes;
  const size_t need1 = csr_bytes + rs_bytes + ofs_bytes + base_bytes +
                       wt_bytes + ovl_bytes;

  const int nchunks = (nNodes + CHUNK - 1) / CHUNK;
  const size_t e2_bytes  = (size_t)nE * 8;
  const size_t int_bytes = (size_t)(3 * nNodes + 1 + 2 * nchunks) * 4;
  const size_t need2 = e2_bytes + int_bytes;

  if (ws_size >= need1 && nNodes <= NB_MAX * 128 && nC <= MAXC) {
    char* p = (char*)d_ws;
    int2* csr = (int2*)p;                       p += csr_bytes;
    int* row_start = (int*)p;                   p += rs_bytes;
    unsigned short* ofs = (unsigned short*)p;   p += ofs_bytes;
    int* bases = (int*)p;                       p += base_bytes;
    unsigned short* wt = (unsigned short*)p;    p += wt_bytes;
    int2* tmp = (int2*)p;           // overlay: edges during CSR build,
    ushort4* xb4 = (ushort4*)p;     // then bf16 x-table for gather

    chunk_sort_kernel<<<nC, 256, 0, stream>>>(esrc, edst, adj, tmp, ofs, nE, nB);
    bucket_scan_kernel<<<1, 1024, 0, stream>>>(ofs, bases, row_start, nC, nB,
                                               nE, nNodes);
    bucket_csr_kernel<<<nB, 256, 0, stream>>>(tmp, ofs, bases, csr, row_start,
                                              nC, nB, nNodes);
    convert_kernel<<<(n4 + 255) / 256, 256, 0, stream>>>((const float4*)x, xb4, n4);
    wt_convert_kernel<<<64, 256, 0, stream>>>(w, wt);
    gather_pack_kernel<<<(nNodes * 32 + 255) / 256, 256, 0, stream>>>(
        (const uint2*)xb4, row_start, csr, (char*)d_out, nNodes);
    gemm_mfma_kernel<<<(nNodes + 127) / 128, 256, 0, stream>>>(
        (const char*)d_out, wt, y, bias, out, nNodes);
  } else if (ws_size >= need2) {
    char* base = (char*)d_ws;
    int2* edges = (int2*)base;
    int* counts = (int*)(base + e2_bytes);
    int* row_start = counts + nNodes;
    int* cursor = row_start + nNodes + 1;
    int* chunk_sum = cursor + nNodes;
    int* chunk_off = chunk_sum + nchunks;

    zero_counts_kernel<<<(nNodes + 255) / 256, 256, 0, stream>>>(counts, nNodes);
    hist_kernel<<<(nE + 255) / 256, 256, 0, stream>>>(edst, counts, nE);
    scan_partial_kernel<<<nchunks, 256, 0, stream>>>(counts, chunk_sum, nNodes);
    scan_chunks_kernel<<<1, 64, 0, stream>>>(chunk_sum, chunk_off, row_start,
                                             nchunks, nNodes);
    scan_final_kernel<<<nchunks, 256, 0, stream>>>(counts, chunk_off, row_start,
                                                   cursor, nNodes);
    scatter_sort_kernel<<<(nE + 255) / 256, 256, 0, stream>>>(
        esrc, edst, adj, cursor, edges, nE);
    gather_fp32_kernel<<<(nNodes * 32 + 255) / 256, 256, 0, stream>>>(
        x, row_start, edges, out, nNodes);
    gemm_fused_kernel<<<(nNodes + 31) / 32, 256, 0, stream>>>(out, w, y, bias,
                                                              nNodes);
  } else {
    zero_kernel<<<(n4 + 255) / 256, 256, 0, stream>>>((float4*)out, n4);
    scatter_atomic_kernel<<<((size_t)nE * 32 + 255) / 256, 256, 0, stream>>>(
        x, esrc, edst, adj, out, nE);
    gemm_fused_kernel<<<(nNodes + 31) / 32, 256, 0, stream>>>(out, w, y, bias,
                                                              nNodes);
  }
}

// Round 8
// 375.698 us; speedup vs baseline: 4.1058x; 1.1112x over previous
//
#include <hip/hip_runtime.h>

#define D 128
#define CE 8192          // edges per sort chunk
#define NB_MAX 1024      // max buckets of 128 nodes -> nNodes <= 131072
#define MAXC 512         // max chunks
#define CHUNK 1024       // tier-2 scan chunk
#define WTP 136          // Wt row pitch in ushorts

// out = relu( (sum_e a_e * x[src_e]) @ W + y + bias )   [linearity of GEMM]
// Round 8: parallel bucket totals/scan, lane-dense bucket_csr (binary search
// over segment prefix), fused convert+wt. Gather/MFMA-GEMM unchanged.

typedef __attribute__((ext_vector_type(8))) short bf16x8;
typedef __attribute__((ext_vector_type(4))) float f32x4;

__device__ __forceinline__ unsigned short f2bf(float f) {
  unsigned u = __float_as_uint(f);
  unsigned r = (u + 0x7fffu + ((u >> 16) & 1u)) >> 16;  // RNE
  return (unsigned short)r;
}

// ============ x -> bf16 table, fused with W -> bf16 Wt[n][k] ===============
__global__ __launch_bounds__(256) void convert_kernel(
    const float4* __restrict__ x4, ushort4* __restrict__ xb4, int n4, int nxblk,
    const float* __restrict__ w, unsigned short* __restrict__ wt) {
  int bid = blockIdx.x;
  if (bid < nxblk) {
    int i = bid * 256 + threadIdx.x;
    if (i < n4) {
      float4 v = x4[i];
      ushort4 r;
      r.x = f2bf(v.x);
      r.y = f2bf(v.y);
      r.z = f2bf(v.z);
      r.w = f2bf(v.w);
      xb4[i] = r;
    }
  } else {
    int idx = (bid - nxblk) * 256 + threadIdx.x;  // 16384 threads
    int n = idx >> 7, k = idx & 127;
    wt[n * WTP + k] = f2bf(w[k * D + n]);
  }
}

// ===================== K2a: block-local counting sort ======================
// Record: int2{ src | (dst&127)<<17 , bits(adj) }. Writes coalesced.
__global__ __launch_bounds__(256) void chunk_sort_kernel(
    const int* __restrict__ src, const int* __restrict__ dst,
    const float* __restrict__ adj, int2* __restrict__ edges,
    unsigned short* __restrict__ ofs, int nE, int nB) {
  __shared__ int2 stage[CE];       // 64 KB
  __shared__ int h[NB_MAX + 4];
  __shared__ int tsum[256];
  const int t = threadIdx.x;
  const int c = blockIdx.x;
  const int e0 = c * CE;
  const int n = min(CE, nE - e0);

  for (int i = t; i < NB_MAX + 4; i += 256) h[i] = 0;
  __syncthreads();

  for (int i = t; i < n; i += 256) atomicAdd(&h[dst[e0 + i] >> 7], 1);
  __syncthreads();

  const int base = t * 4;
  int v0 = h[base], v1 = h[base + 1], v2 = h[base + 2], v3 = h[base + 3];
  int s = v0 + v1 + v2 + v3;
  tsum[t] = s;
  __syncthreads();
  for (int off = 1; off < 256; off <<= 1) {
    int u = (t >= off) ? tsum[t - off] : 0;
    __syncthreads();
    tsum[t] += u;
    __syncthreads();
  }
  int excl = tsum[t] - s;
  h[base] = excl;
  h[base + 1] = excl + v0;
  h[base + 2] = excl + v0 + v1;
  h[base + 3] = excl + v0 + v1 + v2;
  __syncthreads();

  unsigned short* o = ofs + (size_t)c * (nB + 1);
  for (int i = t; i <= nB; i += 256) o[i] = (unsigned short)h[i];
  __syncthreads();

  for (int i = t; i < n; i += 256) {
    int e = e0 + i;
    int d = dst[e];
    int pos = atomicAdd(&h[d >> 7], 1);
    int2 ev;
    ev.x = src[e] | ((d & 127) << 17);
    ev.y = __float_as_int(adj[e]);
    stage[pos] = ev;
  }
  __syncthreads();

  for (int i = t; i < n; i += 256) edges[e0 + i] = stage[i];
}

// ======= K2b1: per-bucket partial totals (4 partials/bucket, parallel) =====
__global__ __launch_bounds__(256) void bucket_partial_kernel(
    const unsigned short* __restrict__ ofs, int* __restrict__ btot4,
    int nC, int nB) {
  int tid = blockIdx.x * 256 + threadIdx.x;
  int b = tid >> 2, part = tid & 3;
  if (b >= nB) return;
  int s = 0;
  for (int c = part; c < nC; c += 4) {
    const unsigned short* oc = ofs + (size_t)c * (nB + 1);
    s += (int)oc[b + 1] - (int)oc[b];
  }
  btot4[tid] = s;
}

// ======= K2b2: exclusive scan of bucket totals -> bases ====================
__global__ __launch_bounds__(1024) void scan_bases_kernel(
    const int* __restrict__ btot4, int* __restrict__ bases,
    int* __restrict__ row_start, int nB, int nE, int nNodes) {
  __shared__ int s[1024];
  const int t = threadIdx.x;
  int tot = 0;
  if (t < nB) {
    int4 v = ((const int4*)btot4)[t];
    tot = v.x + v.y + v.z + v.w;
  }
  s[t] = tot;
  __syncthreads();
  for (int off = 1; off < 1024; off <<= 1) {
    int v = (t >= off) ? s[t - off] : 0;
    __syncthreads();
    s[t] += v;
    __syncthreads();
  }
  if (t < nB) bases[t] = s[t] - tot;  // exclusive
  if (t == 0) {
    bases[nB] = nE;
    row_start[nNodes] = nE;
  }
}

// ===== K2c: per-bucket node CSR, lane-dense via segment-prefix bsearch =====
__global__ __launch_bounds__(256) void bucket_csr_kernel(
    const int2* __restrict__ tmp, const unsigned short* __restrict__ ofs,
    const int* __restrict__ bases, int2* __restrict__ csr,
    int* __restrict__ row_start, int nC, int nB, int nNodes) {
  __shared__ int segst[MAXC];
  __shared__ int pref[MAXC + 1];
  __shared__ int cnt[128];
  __shared__ int cur[128];
  __shared__ int sc[128];
  __shared__ int stot[256];
  const int t = threadIdx.x;
  const int b = blockIdx.x;

  // load segment starts/counts (2 per thread), build prefix
  const int c0 = 2 * t, c1 = 2 * t + 1;
  int n0 = 0, n1 = 0;
  if (c0 < nC) {
    int s0 = ofs[(size_t)c0 * (nB + 1) + b];
    int s1 = ofs[(size_t)c0 * (nB + 1) + b + 1];
    segst[c0] = c0 * CE + s0;
    n0 = s1 - s0;
  }
  if (c1 < nC) {
    int s0 = ofs[(size_t)c1 * (nB + 1) + b];
    int s1 = ofs[(size_t)c1 * (nB + 1) + b + 1];
    segst[c1] = c1 * CE + s0;
    n1 = s1 - s0;
  }
  int tt = n0 + n1;
  stot[t] = tt;
  if (t < 128) cnt[t] = 0;
  __syncthreads();
  for (int off = 1; off < 256; off <<= 1) {
    int v = (t >= off) ? stot[t - off] : 0;
    __syncthreads();
    stot[t] += v;
    __syncthreads();
  }
  int excl = stot[t] - tt;
  if (c0 < nC) pref[c0] = excl;
  if (c1 < nC) pref[c1] = excl + n0;
  if (t == 255) pref[nC] = stot[255];
  __syncthreads();
  const int m = pref[nC];  // edges in this bucket

  // pass 1: per-node counts (all lanes dense)
  for (int i = t; i < m; i += 256) {
    int lo = 0, hi = nC;
    while (hi - lo > 1) {
      int mid = (lo + hi) >> 1;
      if (pref[mid] <= i) lo = mid; else hi = mid;
    }
    int r = tmp[segst[lo] + (i - pref[lo])].x;
    atomicAdd(&cnt[(r >> 17) & 127], 1);
  }
  __syncthreads();

  // scan node counts
  if (t < 128) sc[t] = cnt[t];
  __syncthreads();
  for (int off = 1; off < 128; off <<= 1) {
    int v = 0;
    if (t < 128 && t >= off) v = sc[t - off];
    __syncthreads();
    if (t < 128) sc[t] += v;
    __syncthreads();
  }
  const int base = bases[b];
  if (t < 128) {
    int ex = sc[t] - cnt[t];
    cur[t] = ex;
    int node = (b << 7) + t;
    if (node < nNodes) row_start[node] = base + ex;
  }
  __syncthreads();

  // pass 2: scatter into node-grouped CSR (XCD-local region)
  for (int i = t; i < m; i += 256) {
    int lo = 0, hi = nC;
    while (hi - lo > 1) {
      int mid = (lo + hi) >> 1;
      if (pref[mid] <= i) lo = mid; else hi = mid;
    }
    int2 e = tmp[segst[lo] + (i - pref[lo])];
    int dl = (e.x >> 17) & 127;
    int pos = atomicAdd(&cur[dl], 1);
    int2 rec;
    rec.x = e.x & 0x1FFFF;
    rec.y = e.y;
    csr[(size_t)base + pos] = rec;
  }
}

// ========== Gather -> packed bf16 agg rows inside d_out (512B pitch) =======
__global__ __launch_bounds__(256) void gather_pack_kernel(
    const uint2* __restrict__ xb, const int* __restrict__ row_start,
    const int2* __restrict__ edges, char* out, int nNodes) {
  int g = (blockIdx.x * 256 + threadIdx.x) >> 5;
  int q = threadIdx.x & 31;
  if (g >= nNodes) return;
  int beg = row_start[g], end = row_start[g + 1];
  float4 acc = make_float4(0.f, 0.f, 0.f, 0.f);
  int j = beg;
  for (; j + 1 < end; j += 2) {
    int2 e0 = edges[j], e1 = edges[j + 1];
    float a0 = __int_as_float(e0.y), a1 = __int_as_float(e1.y);
    uint2 v0 = xb[(size_t)e0.x * 32 + q];
    uint2 v1 = xb[(size_t)e1.x * 32 + q];
    acc.x = fmaf(a0, __uint_as_float(v0.x << 16), acc.x);
    acc.y = fmaf(a0, __uint_as_float(v0.x & 0xffff0000u), acc.y);
    acc.z = fmaf(a0, __uint_as_float(v0.y << 16), acc.z);
    acc.w = fmaf(a0, __uint_as_float(v0.y & 0xffff0000u), acc.w);
    acc.x = fmaf(a1, __uint_as_float(v1.x << 16), acc.x);
    acc.y = fmaf(a1, __uint_as_float(v1.x & 0xffff0000u), acc.y);
    acc.z = fmaf(a1, __uint_as_float(v1.y << 16), acc.z);
    acc.w = fmaf(a1, __uint_as_float(v1.y & 0xffff0000u), acc.w);
  }
  if (j < end) {
    int2 e0 = edges[j];
    float a0 = __int_as_float(e0.y);
    uint2 v0 = xb[(size_t)e0.x * 32 + q];
    acc.x = fmaf(a0, __uint_as_float(v0.x << 16), acc.x);
    acc.y = fmaf(a0, __uint_as_float(v0.x & 0xffff0000u), acc.y);
    acc.z = fmaf(a0, __uint_as_float(v0.y << 16), acc.z);
    acc.w = fmaf(a0, __uint_as_float(v0.y & 0xffff0000u), acc.w);
  }
  uint2 pk;
  pk.x = (unsigned)f2bf(acc.x) | ((unsigned)f2bf(acc.y) << 16);
  pk.y = (unsigned)f2bf(acc.z) | ((unsigned)f2bf(acc.w) << 16);
  ((uint2*)(out + (size_t)g * 512))[q] = pk;
}

// ===================== MFMA GEMM + epilogue (round-7 proven) ===============
__global__ __launch_bounds__(256) void gemm_mfma_kernel(
    const char* aggb, const unsigned short* __restrict__ wt,
    const float* __restrict__ y, const float* __restrict__ bias,
    float* out, int nNodes) {
  __shared__ unsigned short sWt[D * WTP];  // 34 KB
  const int t = threadIdx.x;
  for (int i = t; i < D * WTP / 8; i += 256)
    ((int4*)sWt)[i] = ((const int4*)wt)[i];
  __syncthreads();

  const int w = t >> 6, l = t & 63;
  const int quad = l >> 4, m = l & 15;
  const int row0 = blockIdx.x * 128 + w * 32;

  const int ar0 = min(row0 + m, nNodes - 1);
  const int ar1 = min(row0 + 16 + m, nNodes - 1);
  const char* pa0 = aggb + (size_t)ar0 * 512;
  const char* pa1 = aggb + (size_t)ar1 * 512;

  f32x4 acc0[8], acc1[8];
#pragma unroll
  for (int nt = 0; nt < 8; ++nt) {
    acc0[nt] = (f32x4){0.f, 0.f, 0.f, 0.f};
    acc1[nt] = (f32x4){0.f, 0.f, 0.f, 0.f};
  }

#pragma unroll
  for (int ks = 0; ks < 4; ++ks) {
    const int kof = ks * 32 + quad * 8;
    bf16x8 a0 = *(const bf16x8*)(pa0 + kof * 2);
    bf16x8 a1 = *(const bf16x8*)(pa1 + kof * 2);
#pragma unroll
    for (int nt = 0; nt < 8; ++nt) {
      bf16x8 b = *(const bf16x8*)&sWt[(nt * 16 + m) * WTP + kof];
      acc0[nt] = __builtin_amdgcn_mfma_f32_16x16x32_bf16(a0, b, acc0[nt], 0, 0, 0);
      acc1[nt] = __builtin_amdgcn_mfma_f32_16x16x32_bf16(a1, b, acc1[nt], 0, 0, 0);
    }
  }

  float bv[8];
#pragma unroll
  for (int nt = 0; nt < 8; ++nt) bv[nt] = bias[nt * 16 + m];

#pragma unroll
  for (int s = 0; s < 2; ++s) {
#pragma unroll
    for (int r = 0; r < 4; ++r) {
      int row = row0 + s * 16 + quad * 4 + r;
      if (row >= nNodes) continue;
      const float* yr = y + (size_t)row * D;
      float* orow = out + (size_t)row * D;
#pragma unroll
      for (int nt = 0; nt < 8; ++nt) {
        int c = nt * 16 + m;
        float v = (s == 0 ? acc0[nt][r] : acc1[nt][r]) + yr[c] + bv[nt];
        orow[c] = fmaxf(v, 0.f);
      }
    }
  }
}

// ======================= tier-2/3 fallbacks (proven) =======================
__global__ __launch_bounds__(256) void zero_counts_kernel(int* __restrict__ c, int n) {
  int i = blockIdx.x * 256 + threadIdx.x;
  if (i < n) c[i] = 0;
}

__global__ __launch_bounds__(256) void hist_kernel(
    const int* __restrict__ dst, int* __restrict__ counts, int nE) {
  int e = blockIdx.x * 256 + threadIdx.x;
  if (e < nE) atomicAdd(&counts[dst[e]], 1);
}

__global__ __launch_bounds__(256) void scan_partial_kernel(
    const int* __restrict__ counts, int* __restrict__ chunk_sum, int n) {
  __shared__ int sdata[256];
  int b = blockIdx.x, t = threadIdx.x;
  int base = b * CHUNK + t * 4;
  int s = 0;
#pragma unroll
  for (int k = 0; k < 4; ++k) {
    int i = base + k;
    if (i < n) s += counts[i];
  }
  sdata[t] = s;
  __syncthreads();
  for (int off = 128; off > 0; off >>= 1) {
    if (t < off) sdata[t] += sdata[t + off];
    __syncthreads();
  }
  if (t == 0) chunk_sum[b] = sdata[0];
}

__global__ void scan_chunks_kernel(const int* __restrict__ chunk_sum,
                                   int* __restrict__ chunk_off,
                                   int* __restrict__ row_start, int nchunks, int n) {
  if (threadIdx.x == 0 && blockIdx.x == 0) {
    int run = 0;
    for (int i = 0; i < nchunks; ++i) {
      chunk_off[i] = run;
      run += chunk_sum[i];
    }
    row_start[n] = run;
  }
}

__global__ __launch_bounds__(256) void scan_final_kernel(
    const int* __restrict__ counts, const int* __restrict__ chunk_off,
    int* __restrict__ row_start, int* __restrict__ cursor, int n) {
  __shared__ int sdata[256];
  int b = blockIdx.x, t = threadIdx.x;
  int base = b * CHUNK + t * 4;
  int c[4] = {0, 0, 0, 0};
#pragma unroll
  for (int k = 0; k < 4; ++k) {
    int i = base + k;
    if (i < n) c[k] = counts[i];
  }
  int tsum = c[0] + c[1] + c[2] + c[3];
  sdata[t] = tsum;
  __syncthreads();
  for (int off = 1; off < 256; off <<= 1) {
    int v = (t >= off) ? sdata[t - off] : 0;
    __syncthreads();
    sdata[t] += v;
    __syncthreads();
  }
  int run = sdata[t] - tsum + chunk_off[b];
#pragma unroll
  for (int k = 0; k < 4; ++k) {
    int i = base + k;
    if (i < n) {
      row_start[i] = run;
      cursor[i] = run;
      run += c[k];
    }
  }
}

__global__ __launch_bounds__(256) void scatter_sort_kernel(
    const int* __restrict__ src, const int* __restrict__ dst,
    const float* __restrict__ adj, int* __restrict__ cursor,
    int2* __restrict__ edges, int nE) {
  int e = blockIdx.x * 256 + threadIdx.x;
  if (e >= nE) return;
  int d = dst[e];
  int2 ev;
  ev.x = src[e];
  ev.y = __float_as_int(adj[e]);
  int pos = atomicAdd(&cursor[d], 1);
  edges[pos] = ev;
}

__global__ __launch_bounds__(256) void gather_fp32_kernel(
    const float* __restrict__ x, const int* __restrict__ row_start,
    const int2* __restrict__ edges, float* __restrict__ out, int nNodes) {
  int g = (blockIdx.x * 256 + threadIdx.x) >> 5;
  int q = threadIdx.x & 31;
  if (g >= nNodes) return;
  int beg = row_start[g], end = row_start[g + 1];
  const float4* x4 = (const float4*)x;
  float4 acc = make_float4(0.f, 0.f, 0.f, 0.f);
  for (int j = beg; j < end; ++j) {
    int2 e0 = edges[j];
    float a0 = __int_as_float(e0.y);
    float4 v0 = x4[(size_t)e0.x * 32 + q];
    acc.x = fmaf(a0, v0.x, acc.x);
    acc.y = fmaf(a0, v0.y, acc.y);
    acc.z = fmaf(a0, v0.z, acc.z);
    acc.w = fmaf(a0, v0.w, acc.w);
  }
  ((float4*)out)[(size_t)g * 32 + q] = acc;
}

__global__ __launch_bounds__(256) void zero_kernel(float4* __restrict__ out, int n4) {
  int i = blockIdx.x * 256 + threadIdx.x;
  if (i < n4) out[i] = make_float4(0.f, 0.f, 0.f, 0.f);
}

__global__ __launch_bounds__(256) void scatter_atomic_kernel(
    const float* __restrict__ x, const int* __restrict__ src,
    const int* __restrict__ dst, const float* __restrict__ adj,
    float* __restrict__ out, int nE) {
  int tid = blockIdx.x * 256 + threadIdx.x;
  int e = tid >> 5;
  int q = tid & 31;
  if (e >= nE) return;
  int s = src[e];
  int d = dst[e];
  float a = adj[e];
  float4 v = ((const float4*)x)[(size_t)s * 32 + q];
  float* o = out + (size_t)d * D + q * 4;
  atomicAdd(o + 0, v.x * a);
  atomicAdd(o + 1, v.y * a);
  atomicAdd(o + 2, v.z * a);
  atomicAdd(o + 3, v.w * a);
}

// tier-2/3 epilogue GEMM (fp32 in-place)
__global__ __launch_bounds__(256) void gemm_fused_kernel(
    float* __restrict__ out, const float* __restrict__ w,
    const float* __restrict__ y, const float* __restrict__ bias, int nrows) {
  __shared__ float sW[D * D];
  __shared__ float sA[32 * D];
  const int tid = threadIdx.x;
  const int row0 = blockIdx.x * 32;

  const float4* w4 = (const float4*)w;
  float4* sW4 = (float4*)sW;
  for (int i = tid; i < D * D / 4; i += 256) sW4[i] = w4[i];

  const int nrow_blk = min(32, nrows - row0);
  const float4* out4_base = (const float4*)(out + (size_t)row0 * D);
  float4* sA4 = (float4*)sA;
  for (int i = tid; i < nrow_blk * 32; i += 256) sA4[i] = out4_base[i];
  __syncthreads();

  const int cg = tid & 31;
  const int rs = tid >> 5;

  float4 acc[4];
#pragma unroll
  for (int r = 0; r < 4; ++r) acc[r] = make_float4(0.f, 0.f, 0.f, 0.f);

#pragma unroll 4
  for (int k4 = 0; k4 < 32; ++k4) {
    float4 wv0 = sW4[(k4 * 4 + 0) * 32 + cg];
    float4 wv1 = sW4[(k4 * 4 + 1) * 32 + cg];
    float4 wv2 = sW4[(k4 * 4 + 2) * 32 + cg];
    float4 wv3 = sW4[(k4 * 4 + 3) * 32 + cg];
#pragma unroll
    for (int r = 0; r < 4; ++r) {
      float4 xv = sA4[(rs + r * 8) * 32 + k4];
      acc[r].x = fmaf(xv.x, wv0.x, acc[r].x);
      acc[r].y = fmaf(xv.x, wv0.y, acc[r].y);
      acc[r].z = fmaf(xv.x, wv0.z, acc[r].z);
      acc[r].w = fmaf(xv.x, wv0.w, acc[r].w);
      acc[r].x = fmaf(xv.y, wv1.x, acc[r].x);
      acc[r].y = fmaf(xv.y, wv1.y, acc[r].y);
      acc[r].z = fmaf(xv.y, wv1.z, acc[r].z);
      acc[r].w = fmaf(xv.y, wv1.w, acc[r].w);
      acc[r].x = fmaf(xv.z, wv2.x, acc[r].x);
      acc[r].y = fmaf(xv.z, wv2.y, acc[r].y);
      acc[r].z = fmaf(xv.z, wv2.z, acc[r].z);
      acc[r].w = fmaf(xv.z, wv2.w, acc[r].w);
      acc[r].x = fmaf(xv.w, wv3.x, acc[r].x);
      acc[r].y = fmaf(xv.w, wv3.y, acc[r].y);
      acc[r].z = fmaf(xv.w, wv3.z, acc[r].z);
      acc[r].w = fmaf(xv.w, wv3.w, acc[r].w);
    }
  }

  const float4* y4 = (const float4*)y;
  const float4* b4 = (const float4*)bias;
  float4* o4 = (float4*)out;
  float4 bv = b4[cg];
#pragma unroll
  for (int r = 0; r < 4; ++r) {
    int row = row0 + rs + r * 8;
    if (row < nrows) {
      float4 yv = y4[(size_t)row * 32 + cg];
      float4 res;
      res.x = fmaxf(acc[r].x + yv.x + bv.x, 0.f);
      res.y = fmaxf(acc[r].y + yv.y + bv.y, 0.f);
      res.z = fmaxf(acc[r].z + yv.z + bv.z, 0.f);
      res.w = fmaxf(acc[r].w + yv.w + bv.w, 0.f);
      o4[(size_t)row * 32 + cg] = res;
    }
  }
}

extern "C" void kernel_launch(void* const* d_in, const int* in_sizes, int n_in,
                              void* d_out, int out_size, void* d_ws, size_t ws_size,
                              hipStream_t stream) {
  const float* x    = (const float*)d_in[0];
  const float* y    = (const float*)d_in[1];
  const int*   esrc = (const int*)d_in[2];
  const int*   edst = (const int*)d_in[3];
  const float* adj  = (const float*)d_in[4];
  const float* w    = (const float*)d_in[5];
  const float* bias = (const float*)d_in[6];
  float* out = (float*)d_out;

  const int nNodes = in_sizes[0] / D;
  const int nE = in_sizes[2];
  const int n4 = nNodes * (D / 4);
  const int nB = (nNodes + 127) >> 7;
  const int nC = (nE + CE - 1) / CE;

  // tier-1 ws: [csr | row_start | ofs | bases | btot4 | wt | overlay(tmp->xb)]
  const size_t csr_bytes   = (size_t)nE * 8;
  const size_t rs_bytes    = (size_t)(nNodes + 1) * 4;
  const size_t ofs_bytes   = (((size_t)nC * (nB + 1) * 2) + 15) & ~(size_t)15;
  const size_t base_bytes  = (((size_t)(nB + 1) * 4) + 15) & ~(size_t)15;
  const size_t btot4_bytes = (((size_t)nB * 4 * 4) + 15) & ~(size_t)15;
  const size_t wt_bytes    = (size_t)D * WTP * 2;
  const size_t tmp_bytes   = (size_t)nC * CE * 8;
  const size_t xb_bytes    = (size_t)nNodes * D * 2;
  const size_t ovl_bytes   = tmp_bytes > xb_bytes ? tmp_bytes : xb_bytes;
  const size_t need1 = csr_bytes + rs_bytes + ofs_bytes + base_bytes +
                       btot4_bytes + wt_bytes + ovl_bytes;

  const int nchunks = (nNodes + CHUNK - 1) / CHUNK;
  const size_t e2_bytes  = (size_t)nE * 8;
  const size_t int_bytes = (size_t)(3 * nNodes + 1 + 2 * nchunks) * 4;
  const size_t need2 = e2_bytes + int_bytes;

  if (ws_size >= need1 && nNodes <= NB_MAX * 128 && nC <= MAXC) {
    char* p = (char*)d_ws;
    int2* csr = (int2*)p;                       p += csr_bytes;
    int* row_start = (int*)p;                   p += rs_bytes;
    unsigned short* ofs = (unsigned short*)p;   p += ofs_bytes;
    int* bases = (int*)p;                       p += base_bytes;
    int* btot4 = (int*)p;                       p += btot4_bytes;
    unsigned short* wt = (unsigned short*)p;    p += wt_bytes;
    int2* tmp = (int2*)p;           // overlay: edges during CSR build,
    ushort4* xb4 = (ushort4*)p;     // then bf16 x-table for gather

    const int nxblk = (n4 + 255) / 256;
    chunk_sort_kernel<<<nC, 256, 0, stream>>>(esrc, edst, adj, tmp, ofs, nE, nB);
    bucket_partial_kernel<<<(nB * 4 + 255) / 256, 256, 0, stream>>>(
        ofs, btot4, nC, nB);
    scan_bases_kernel<<<1, 1024, 0, stream>>>(btot4, bases, row_start, nB, nE,
                                              nNodes);
    bucket_csr_kernel<<<nB, 256, 0, stream>>>(tmp, ofs, bases, csr, row_start,
                                              nC, nB, nNodes);
    convert_kernel<<<nxblk + 64, 256, 0, stream>>>((const float4*)x, xb4, n4,
                                                   nxblk, w, wt);
    gather_pack_kernel<<<(nNodes * 32 + 255) / 256, 256, 0, stream>>>(
        (const uint2*)xb4, row_start, csr, (char*)d_out, nNodes);
    gemm_mfma_kernel<<<(nNodes + 127) / 128, 256, 0, stream>>>(
        (const char*)d_out, wt, y, bias, out, nNodes);
  } else if (ws_size >= need2) {
    char* base = (char*)d_ws;
    int2* edges = (int2*)base;
    int* counts = (int*)(base + e2_bytes);
    int* row_start = counts + nNodes;
    int* cursor = row_start + nNodes + 1;
    int* chunk_sum = cursor + nNodes;
    int* chunk_off = chunk_sum + nchunks;

    zero_counts_kernel<<<(nNodes + 255) / 256, 256, 0, stream>>>(counts, nNodes);
    hist_kernel<<<(nE + 255) / 256, 256, 0, stream>>>(edst, counts, nE);
    scan_partial_kernel<<<nchunks, 256, 0, stream>>>(counts, chunk_sum, nNodes);
    scan_chunks_kernel<<<1, 64, 0, stream>>>(chunk_sum, chunk_off, row_start,
                                             nchunks, nNodes);
    scan_final_kernel<<<nchunks, 256, 0, stream>>>(counts, chunk_off, row_start,
                                                   cursor, nNodes);
    scatter_sort_kernel<<<(nE + 255) / 256, 256, 0, stream>>>(
        esrc, edst, adj, cursor, edges, nE);
    gather_fp32_kernel<<<(nNodes * 32 + 255) / 256, 256, 0, stream>>>(
        x, row_start, edges, out, nNodes);
    gemm_fused_kernel<<<(nNodes + 31) / 32, 256, 0, stream>>>(out, w, y, bias,
                                                              nNodes);
  } else {
    zero_kernel<<<(n4 + 255) / 256, 256, 0, stream>>>((float4*)out, n4);
    scatter_atomic_kernel<<<((size_t)nE * 32 + 255) / 256, 256, 0, stream>>>(
        x, esrc, edst, adj, out, nE);
    gemm_fused_kernel<<<(nNodes + 31) / 32, 256, 0, stream>>>(out, w, y, bias,
                                                              nNodes);
  }
}

// Round 9
// 330.296 us; speedup vs baseline: 4.6702x; 1.1375x over previous
//
#include <hip/hip_runtime.h>

#define D 128
#define CE 8192          // edges per sort chunk
#define NB_MAX 1024      // max buckets of 128 nodes -> nNodes <= 131072
#define MAXC 512         // max chunks
#define EBUF 3072        // bucket_csr LDS edge stash capacity
#define CHUNK 1024       // tier-2 scan chunk
#define WTP 136          // Wt row pitch in ushorts

// out = relu( (sum_e a_e * x[src_e]) @ W + y + bias )   [linearity of GEMM]
// Round 9: 1024-thr chunk_sort w/ register dst-stash, per-bucket tot kernel,
// bucket_csr LDS edge stash, gather unroll-4. Gather/MFMA-GEMM core unchanged.

typedef __attribute__((ext_vector_type(8))) short bf16x8;
typedef __attribute__((ext_vector_type(4))) float f32x4;

__device__ __forceinline__ unsigned short f2bf(float f) {
  unsigned u = __float_as_uint(f);
  unsigned r = (u + 0x7fffu + ((u >> 16) & 1u)) >> 16;  // RNE
  return (unsigned short)r;
}

// ============ x -> bf16 table, fused with W -> bf16 Wt[n][k] ===============
__global__ __launch_bounds__(256) void convert_kernel(
    const float4* __restrict__ x4, ushort4* __restrict__ xb4, int n4, int nxblk,
    const float* __restrict__ w, unsigned short* __restrict__ wt) {
  int bid = blockIdx.x;
  if (bid < nxblk) {
    int i = bid * 256 + threadIdx.x;
    if (i < n4) {
      float4 v = x4[i];
      ushort4 r;
      r.x = f2bf(v.x);
      r.y = f2bf(v.y);
      r.z = f2bf(v.z);
      r.w = f2bf(v.w);
      xb4[i] = r;
    }
  } else {
    int idx = (bid - nxblk) * 256 + threadIdx.x;  // 16384 threads
    int n = idx >> 7, k = idx & 127;
    wt[n * WTP + k] = f2bf(w[k * D + n]);
  }
}

// ========== K2a: block-local counting sort, 1024 threads ===================
// 8 edges/thread; dst stashed in registers between hist and scatter passes.
// Record: int2{ src | (dst&127)<<17 , bits(adj) }. Global writes coalesced.
__global__ __launch_bounds__(1024) void chunk_sort_kernel(
    const int* __restrict__ src, const int* __restrict__ dst,
    const float* __restrict__ adj, int2* __restrict__ edges,
    unsigned short* __restrict__ ofs, int nE, int nB) {
  __shared__ int2 stage[CE];       // 64 KB
  __shared__ int h[NB_MAX + 4];    // 4.1 KB: hist -> starts -> cursors
  __shared__ int tsum[1024];       // 4 KB
  const int t = threadIdx.x;
  const int c = blockIdx.x;
  const int e0 = c * CE;
  const int n = min(CE, nE - e0);

  for (int i = t; i < NB_MAX + 4; i += 1024) h[i] = 0;
  __syncthreads();

  int dreg[8];
#pragma unroll
  for (int k = 0; k < 8; ++k) {
    int i = k * 1024 + t;
    if (i < n) {
      int d = dst[e0 + i];
      dreg[k] = d;
      atomicAdd(&h[d >> 7], 1);
    }
  }
  __syncthreads();

  // exclusive scan over 1024 bucket counts, one per thread
  int v = h[t];
  tsum[t] = v;
  __syncthreads();
  for (int off = 1; off < 1024; off <<= 1) {
    int u = (t >= off) ? tsum[t - off] : 0;
    __syncthreads();
    tsum[t] += u;
    __syncthreads();
  }
  h[t] = tsum[t] - v;  // exclusive prefix
  __syncthreads();

  // publish bucket starts (buckets >= nB are empty -> h[nB] == n)
  unsigned short* o = ofs + (size_t)c * (nB + 1);
  for (int i = t; i <= nB; i += 1024)
    o[i] = (unsigned short)(i < NB_MAX ? h[i] : n);
  __syncthreads();

  // scatter into LDS stage via per-bucket cursors (dst from registers)
#pragma unroll
  for (int k = 0; k < 8; ++k) {
    int i = k * 1024 + t;
    if (i < n) {
      int d = dreg[k];
      int pos = atomicAdd(&h[d >> 7], 1);
      int2 ev;
      ev.x = src[e0 + i] | ((d & 127) << 17);
      ev.y = __float_as_int(adj[e0 + i]);
      stage[pos] = ev;
    }
  }
  __syncthreads();

  // coalesced write-out
  for (int i = t; i < n; i += 1024) edges[e0 + i] = stage[i];
}

// ======= K2b1: per-bucket totals (one block per bucket, parallel) ==========
__global__ __launch_bounds__(256) void bucket_tot_kernel(
    const unsigned short* __restrict__ ofs, int* __restrict__ btot,
    int nC, int nB) {
  __shared__ int red[256];
  const int b = blockIdx.x;
  const int t = threadIdx.x;
  int s = 0;
  for (int c = t; c < nC; c += 256) {
    const unsigned short* oc = ofs + (size_t)c * (nB + 1);
    s += (int)oc[b + 1] - (int)oc[b];
  }
  red[t] = s;
  __syncthreads();
  for (int off = 128; off > 0; off >>= 1) {
    if (t < off) red[t] += red[t + off];
    __syncthreads();
  }
  if (t == 0) btot[b] = red[0];
}

// ======= K2b2: exclusive scan of bucket totals -> bases ====================
__global__ __launch_bounds__(1024) void scan_bases_kernel(
    const int* __restrict__ btot, int* __restrict__ bases,
    int* __restrict__ row_start, int nB, int nE, int nNodes) {
  __shared__ int s[1024];
  const int t = threadIdx.x;
  int tot = (t < nB) ? btot[t] : 0;
  s[t] = tot;
  __syncthreads();
  for (int off = 1; off < 1024; off <<= 1) {
    int v = (t >= off) ? s[t - off] : 0;
    __syncthreads();
    s[t] += v;
    __syncthreads();
  }
  if (t < nB) bases[t] = s[t] - tot;  // exclusive
  if (t == 0) {
    bases[nB] = nE;
    row_start[nNodes] = nE;
  }
}

// ===== K2c: per-bucket node CSR; pass1 copies bucket edges into LDS ========
__global__ __launch_bounds__(256) void bucket_csr_kernel(
    const int2* __restrict__ tmp, const unsigned short* __restrict__ ofs,
    const int* __restrict__ bases, int2* __restrict__ csr,
    int* __restrict__ row_start, int nC, int nB, int nNodes) {
  __shared__ int2 ebuf[EBUF];      // 24 KB edge stash
  __shared__ int segst[MAXC];
  __shared__ int pref[MAXC + 1];
  __shared__ int cnt[128];
  __shared__ int cur[128];
  __shared__ int sc[128];
  __shared__ int stot[256];
  const int t = threadIdx.x;
  const int b = blockIdx.x;

  // load segment starts/counts (2 per thread), build prefix
  const int c0 = 2 * t, c1 = 2 * t + 1;
  int n0 = 0, n1 = 0;
  if (c0 < nC) {
    int s0 = ofs[(size_t)c0 * (nB + 1) + b];
    int s1 = ofs[(size_t)c0 * (nB + 1) + b + 1];
    segst[c0] = c0 * CE + s0;
    n0 = s1 - s0;
  }
  if (c1 < nC) {
    int s0 = ofs[(size_t)c1 * (nB + 1) + b];
    int s1 = ofs[(size_t)c1 * (nB + 1) + b + 1];
    segst[c1] = c1 * CE + s0;
    n1 = s1 - s0;
  }
  int tt = n0 + n1;
  stot[t] = tt;
  if (t < 128) cnt[t] = 0;
  __syncthreads();
  for (int off = 1; off < 256; off <<= 1) {
    int v = (t >= off) ? stot[t - off] : 0;
    __syncthreads();
    stot[t] += v;
    __syncthreads();
  }
  int excl = stot[t] - tt;
  if (c0 < nC) pref[c0] = excl;
  if (c1 < nC) pref[c1] = excl + n0;
  if (t == 255) pref[nC] = stot[255];
  __syncthreads();
  const int m = pref[nC];  // edges in this bucket
  const bool fits = (m <= EBUF);

  // pass 1: bsearch segment, copy edge to LDS (if fits), count nodes
  for (int i = t; i < m; i += 256) {
    int lo = 0, hi = nC;
    while (hi - lo > 1) {
      int mid = (lo + hi) >> 1;
      if (pref[mid] <= i) lo = mid; else hi = mid;
    }
    int2 e = tmp[segst[lo] + (i - pref[lo])];
    if (fits) ebuf[i] = e;
    atomicAdd(&cnt[(e.x >> 17) & 127], 1);
  }
  __syncthreads();

  // scan node counts
  if (t < 128) sc[t] = cnt[t];
  __syncthreads();
  for (int off = 1; off < 128; off <<= 1) {
    int v = 0;
    if (t < 128 && t >= off) v = sc[t - off];
    __syncthreads();
    if (t < 128) sc[t] += v;
    __syncthreads();
  }
  const int base = bases[b];
  if (t < 128) {
    int ex = sc[t] - cnt[t];
    cur[t] = ex;
    int node = (b << 7) + t;
    if (node < nNodes) row_start[node] = base + ex;
  }
  __syncthreads();

  // pass 2: scatter into node-grouped CSR (XCD-local region)
  if (fits) {
    for (int i = t; i < m; i += 256) {
      int2 e = ebuf[i];
      int dl = (e.x >> 17) & 127;
      int pos = atomicAdd(&cur[dl], 1);
      int2 rec;
      rec.x = e.x & 0x1FFFF;
      rec.y = e.y;
      csr[(size_t)base + pos] = rec;
    }
  } else {
    for (int i = t; i < m; i += 256) {
      int lo = 0, hi = nC;
      while (hi - lo > 1) {
        int mid = (lo + hi) >> 1;
        if (pref[mid] <= i) lo = mid; else hi = mid;
      }
      int2 e = tmp[segst[lo] + (i - pref[lo])];
      int dl = (e.x >> 17) & 127;
      int pos = atomicAdd(&cur[dl], 1);
      int2 rec;
      rec.x = e.x & 0x1FFFF;
      rec.y = e.y;
      csr[(size_t)base + pos] = rec;
    }
  }
}

// ========== Gather -> packed bf16 agg rows inside d_out (512B pitch) =======
__global__ __launch_bounds__(256) void gather_pack_kernel(
    const uint2* __restrict__ xb, const int* __restrict__ row_start,
    const int2* __restrict__ edges, char* out, int nNodes) {
  int g = (blockIdx.x * 256 + threadIdx.x) >> 5;
  int q = threadIdx.x & 31;
  if (g >= nNodes) return;
  int beg = row_start[g], end = row_start[g + 1];
  float4 acc = make_float4(0.f, 0.f, 0.f, 0.f);
  int j = beg;
  for (; j + 3 < end; j += 4) {
    int2 e0 = edges[j], e1 = edges[j + 1], e2 = edges[j + 2], e3 = edges[j + 3];
    float a0 = __int_as_float(e0.y), a1 = __int_as_float(e1.y);
    float a2 = __int_as_float(e2.y), a3 = __int_as_float(e3.y);
    uint2 v0 = xb[(size_t)e0.x * 32 + q];
    uint2 v1 = xb[(size_t)e1.x * 32 + q];
    uint2 v2 = xb[(size_t)e2.x * 32 + q];
    uint2 v3 = xb[(size_t)e3.x * 32 + q];
    acc.x = fmaf(a0, __uint_as_float(v0.x << 16), acc.x);
    acc.y = fmaf(a0, __uint_as_float(v0.x & 0xffff0000u), acc.y);
    acc.z = fmaf(a0, __uint_as_float(v0.y << 16), acc.z);
    acc.w = fmaf(a0, __uint_as_float(v0.y & 0xffff0000u), acc.w);
    acc.x = fmaf(a1, __uint_as_float(v1.x << 16), acc.x);
    acc.y = fmaf(a1, __uint_as_float(v1.x & 0xffff0000u), acc.y);
    acc.z = fmaf(a1, __uint_as_float(v1.y << 16), acc.z);
    acc.w = fmaf(a1, __uint_as_float(v1.y & 0xffff0000u), acc.w);
    acc.x = fmaf(a2, __uint_as_float(v2.x << 16), acc.x);
    acc.y = fmaf(a2, __uint_as_float(v2.x & 0xffff0000u), acc.y);
    acc.z = fmaf(a2, __uint_as_float(v2.y << 16), acc.z);
    acc.w = fmaf(a2, __uint_as_float(v2.y & 0xffff0000u), acc.w);
    acc.x = fmaf(a3, __uint_as_float(v3.x << 16), acc.x);
    acc.y = fmaf(a3, __uint_as_float(v3.x & 0xffff0000u), acc.y);
    acc.z = fmaf(a3, __uint_as_float(v3.y << 16), acc.z);
    acc.w = fmaf(a3, __uint_as_float(v3.y & 0xffff0000u), acc.w);
  }
  for (; j < end; ++j) {
    int2 e0 = edges[j];
    float a0 = __int_as_float(e0.y);
    uint2 v0 = xb[(size_t)e0.x * 32 + q];
    acc.x = fmaf(a0, __uint_as_float(v0.x << 16), acc.x);
    acc.y = fmaf(a0, __uint_as_float(v0.x & 0xffff0000u), acc.y);
    acc.z = fmaf(a0, __uint_as_float(v0.y << 16), acc.z);
    acc.w = fmaf(a0, __uint_as_float(v0.y & 0xffff0000u), acc.w);
  }
  uint2 pk;
  pk.x = (unsigned)f2bf(acc.x) | ((unsigned)f2bf(acc.y) << 16);
  pk.y = (unsigned)f2bf(acc.z) | ((unsigned)f2bf(acc.w) << 16);
  ((uint2*)(out + (size_t)g * 512))[q] = pk;
}

// ===================== MFMA GEMM + epilogue (round-7 proven) ===============
__global__ __launch_bounds__(256) void gemm_mfma_kernel(
    const char* aggb, const unsigned short* __restrict__ wt,
    const float* __restrict__ y, const float* __restrict__ bias,
    float* out, int nNodes) {
  __shared__ unsigned short sWt[D * WTP];  // 34 KB
  const int t = threadIdx.x;
  for (int i = t; i < D * WTP / 8; i += 256)
    ((int4*)sWt)[i] = ((const int4*)wt)[i];
  __syncthreads();

  const int w = t >> 6, l = t & 63;
  const int quad = l >> 4, m = l & 15;
  const int row0 = blockIdx.x * 128 + w * 32;

  const int ar0 = min(row0 + m, nNodes - 1);
  const int ar1 = min(row0 + 16 + m, nNodes - 1);
  const char* pa0 = aggb + (size_t)ar0 * 512;
  const char* pa1 = aggb + (size_t)ar1 * 512;

  f32x4 acc0[8], acc1[8];
#pragma unroll
  for (int nt = 0; nt < 8; ++nt) {
    acc0[nt] = (f32x4){0.f, 0.f, 0.f, 0.f};
    acc1[nt] = (f32x4){0.f, 0.f, 0.f, 0.f};
  }

#pragma unroll
  for (int ks = 0; ks < 4; ++ks) {
    const int kof = ks * 32 + quad * 8;
    bf16x8 a0 = *(const bf16x8*)(pa0 + kof * 2);
    bf16x8 a1 = *(const bf16x8*)(pa1 + kof * 2);
#pragma unroll
    for (int nt = 0; nt < 8; ++nt) {
      bf16x8 b = *(const bf16x8*)&sWt[(nt * 16 + m) * WTP + kof];
      acc0[nt] = __builtin_amdgcn_mfma_f32_16x16x32_bf16(a0, b, acc0[nt], 0, 0, 0);
      acc1[nt] = __builtin_amdgcn_mfma_f32_16x16x32_bf16(a1, b, acc1[nt], 0, 0, 0);
    }
  }

  float bv[8];
#pragma unroll
  for (int nt = 0; nt < 8; ++nt) bv[nt] = bias[nt * 16 + m];

#pragma unroll
  for (int s = 0; s < 2; ++s) {
#pragma unroll
    for (int r = 0; r < 4; ++r) {
      int row = row0 + s * 16 + quad * 4 + r;
      if (row >= nNodes) continue;
      const float* yr = y + (size_t)row * D;
      float* orow = out + (size_t)row * D;
#pragma unroll
      for (int nt = 0; nt < 8; ++nt) {
        int c = nt * 16 + m;
        float v = (s == 0 ? acc0[nt][r] : acc1[nt][r]) + yr[c] + bv[nt];
        orow[c] = fmaxf(v, 0.f);
      }
    }
  }
}

// ======================= tier-2/3 fallbacks (proven) =======================
__global__ __launch_bounds__(256) void zero_counts_kernel(int* __restrict__ c, int n) {
  int i = blockIdx.x * 256 + threadIdx.x;
  if (i < n) c[i] = 0;
}

__global__ __launch_bounds__(256) void hist_kernel(
    const int* __restrict__ dst, int* __restrict__ counts, int nE) {
  int e = blockIdx.x * 256 + threadIdx.x;
  if (e < nE) atomicAdd(&counts[dst[e]], 1);
}

__global__ __launch_bounds__(256) void scan_partial_kernel(
    const int* __restrict__ counts, int* __restrict__ chunk_sum, int n) {
  __shared__ int sdata[256];
  int b = blockIdx.x, t = threadIdx.x;
  int base = b * CHUNK + t * 4;
  int s = 0;
#pragma unroll
  for (int k = 0; k < 4; ++k) {
    int i = base + k;
    if (i < n) s += counts[i];
  }
  sdata[t] = s;
  __syncthreads();
  for (int off = 128; off > 0; off >>= 1) {
    if (t < off) sdata[t] += sdata[t + off];
    __syncthreads();
  }
  if (t == 0) chunk_sum[b] = sdata[0];
}

__global__ void scan_chunks_kernel(const int* __restrict__ chunk_sum,
                                   int* __restrict__ chunk_off,
                                   int* __restrict__ row_start, int nchunks, int n) {
  if (threadIdx.x == 0 && blockIdx.x == 0) {
    int run = 0;
    for (int i = 0; i < nchunks; ++i) {
      chunk_off[i] = run;
      run += chunk_sum[i];
    }
    row_start[n] = run;
  }
}

__global__ __launch_bounds__(256) void scan_final_kernel(
    const int* __restrict__ counts, const int* __restrict__ chunk_off,
    int* __restrict__ row_start, int* __restrict__ cursor, int n) {
  __shared__ int sdata[256];
  int b = blockIdx.x, t = threadIdx.x;
  int base = b * CHUNK + t * 4;
  int c[4] = {0, 0, 0, 0};
#pragma unroll
  for (int k = 0; k < 4; ++k) {
    int i = base + k;
    if (i < n) c[k] = counts[i];
  }
  int tsum = c[0] + c[1] + c[2] + c[3];
  sdata[t] = tsum;
  __syncthreads();
  for (int off = 1; off < 256; off <<= 1) {
    int v = (t >= off) ? sdata[t - off] : 0;
    __syncthreads();
    sdata[t] += v;
    __syncthreads();
  }
  int run = sdata[t] - tsum + chunk_off[b];
#pragma unroll
  for (int k = 0; k < 4; ++k) {
    int i = base + k;
    if (i < n) {
      row_start[i] = run;
      cursor[i] = run;
      run += c[k];
    }
  }
}

__global__ __launch_bounds__(256) void scatter_sort_kernel(
    const int* __restrict__ src, const int* __restrict__ dst,
    const float* __restrict__ adj, int* __restrict__ cursor,
    int2* __restrict__ edges, int nE) {
  int e = blockIdx.x * 256 + threadIdx.x;
  if (e >= nE) return;
  int d = dst[e];
  int2 ev;
  ev.x = src[e];
  ev.y = __float_as_int(adj[e]);
  int pos = atomicAdd(&cursor[d], 1);
  edges[pos] = ev;
}

__global__ __launch_bounds__(256) void gather_fp32_kernel(
    const float* __restrict__ x, const int* __restrict__ row_start,
    const int2* __restrict__ edges, float* __restrict__ out, int nNodes) {
  int g = (blockIdx.x * 256 + threadIdx.x) >> 5;
  int q = threadIdx.x & 31;
  if (g >= nNodes) return;
  int beg = row_start[g], end = row_start[g + 1];
  const float4* x4 = (const float4*)x;
  float4 acc = make_float4(0.f, 0.f, 0.f, 0.f);
  for (int j = beg; j < end; ++j) {
    int2 e0 = edges[j];
    float a0 = __int_as_float(e0.y);
    float4 v0 = x4[(size_t)e0.x * 32 + q];
    acc.x = fmaf(a0, v0.x, acc.x);
    acc.y = fmaf(a0, v0.y, acc.y);
    acc.z = fmaf(a0, v0.z, acc.z);
    acc.w = fmaf(a0, v0.w, acc.w);
  }
  ((float4*)out)[(size_t)g * 32 + q] = acc;
}

__global__ __launch_bounds__(256) void zero_kernel(float4* __restrict__ out, int n4) {
  int i = blockIdx.x * 256 + threadIdx.x;
  if (i < n4) out[i] = make_float4(0.f, 0.f, 0.f, 0.f);
}

__global__ __launch_bounds__(256) void scatter_atomic_kernel(
    const float* __restrict__ x, const int* __restrict__ src,
    const int* __restrict__ dst, const float* __restrict__ adj,
    float* __restrict__ out, int nE) {
  int tid = blockIdx.x * 256 + threadIdx.x;
  int e = tid >> 5;
  int q = tid & 31;
  if (e >= nE) return;
  int s = src[e];
  int d = dst[e];
  float a = adj[e];
  float4 v = ((const float4*)x)[(size_t)s * 32 + q];
  float* o = out + (size_t)d * D + q * 4;
  atomicAdd(o + 0, v.x * a);
  atomicAdd(o + 1, v.y * a);
  atomicAdd(o + 2, v.z * a);
  atomicAdd(o + 3, v.w * a);
}

// tier-2/3 epilogue GEMM (fp32 in-place)
__global__ __launch_bounds__(256) void gemm_fused_kernel(
    float* __restrict__ out, const float* __restrict__ w,
    const float* __restrict__ y, const float* __restrict__ bias, int nrows) {
  __shared__ float sW[D * D];
  __shared__ float sA[32 * D];
  const int tid = threadIdx.x;
  const int row0 = blockIdx.x * 32;

  const float4* w4 = (const float4*)w;
  float4* sW4 = (float4*)sW;
  for (int i = tid; i < D * D / 4; i += 256) sW4[i] = w4[i];

  const int nrow_blk = min(32, nrows - row0);
  const float4* out4_base = (const float4*)(out + (size_t)row0 * D);
  float4* sA4 = (float4*)sA;
  for (int i = tid; i < nrow_blk * 32; i += 256) sA4[i] = out4_base[i];
  __syncthreads();

  const int cg = tid & 31;
  const int rs = tid >> 5;

  float4 acc[4];
#pragma unroll
  for (int r = 0; r < 4; ++r) acc[r] = make_float4(0.f, 0.f, 0.f, 0.f);

#pragma unroll 4
  for (int k4 = 0; k4 < 32; ++k4) {
    float4 wv0 = sW4[(k4 * 4 + 0) * 32 + cg];
    float4 wv1 = sW4[(k4 * 4 + 1) * 32 + cg];
    float4 wv2 = sW4[(k4 * 4 + 2) * 32 + cg];
    float4 wv3 = sW4[(k4 * 4 + 3) * 32 + cg];
#pragma unroll
    for (int r = 0; r < 4; ++r) {
      float4 xv = sA4[(rs + r * 8) * 32 + k4];
      acc[r].x = fmaf(xv.x, wv0.x, acc[r].x);
      acc[r].y = fmaf(xv.x, wv0.y, acc[r].y);
      acc[r].z = fmaf(xv.x, wv0.z, acc[r].z);
      acc[r].w = fmaf(xv.x, wv0.w, acc[r].w);
      acc[r].x = fmaf(xv.y, wv1.x, acc[r].x);
      acc[r].y = fmaf(xv.y, wv1.y, acc[r].y);
      acc[r].z = fmaf(xv.y, wv1.z, acc[r].z);
      acc[r].w = fmaf(xv.y, wv1.w, acc[r].w);
      acc[r].x = fmaf(xv.z, wv2.x, acc[r].x);
      acc[r].y = fmaf(xv.z, wv2.y, acc[r].y);
      acc[r].z = fmaf(xv.z, wv2.z, acc[r].z);
      acc[r].w = fmaf(xv.z, wv2.w, acc[r].w);
      acc[r].x = fmaf(xv.w, wv3.x, acc[r].x);
      acc[r].y = fmaf(xv.w, wv3.y, acc[r].y);
      acc[r].z = fmaf(xv.w, wv3.z, acc[r].z);
      acc[r].w = fmaf(xv.w, wv3.w, acc[r].w);
    }
  }

  const float4* y4 = (const float4*)y;
  const float4* b4 = (const float4*)bias;
  float4* o4 = (float4*)out;
  float4 bv = b4[cg];
#pragma unroll
  for (int r = 0; r < 4; ++r) {
    int row = row0 + rs + r * 8;
    if (row < nrows) {
      float4 yv = y4[(size_t)row * 32 + cg];
      float4 res;
      res.x = fmaxf(acc[r].x + yv.x + bv.x, 0.f);
      res.y = fmaxf(acc[r].y + yv.y + bv.y, 0.f);
      res.z = fmaxf(acc[r].z + yv.z + bv.z, 0.f);
      res.w = fmaxf(acc[r].w + yv.w + bv.w, 0.f);
      o4[(size_t)row * 32 + cg] = res;
    }
  }
}

extern "C" void kernel_launch(void* const* d_in, const int* in_sizes, int n_in,
                              void* d_out, int out_size, void* d_ws, size_t ws_size,
                              hipStream_t stream) {
  const float* x    = (const float*)d_in[0];
  const float* y    = (const float*)d_in[1];
  const int*   esrc = (const int*)d_in[2];
  const int*   edst = (const int*)d_in[3];
  const float* adj  = (const float*)d_in[4];
  const float* w    = (const float*)d_in[5];
  const float* bias = (const float*)d_in[6];
  float* out = (float*)d_out;

  const int nNodes = in_sizes[0] / D;
  const int nE = in_sizes[2];
  const int n4 = nNodes * (D / 4);
  const int nB = (nNodes + 127) >> 7;
  const int nC = (nE + CE - 1) / CE;

  // tier-1 ws: [csr | row_start | ofs | bases | btot | wt | overlay(tmp->xb)]
  const size_t csr_bytes  = (size_t)nE * 8;
  const size_t rs_bytes   = (size_t)(nNodes + 1) * 4;
  const size_t ofs_bytes  = (((size_t)nC * (nB + 1) * 2) + 15) & ~(size_t)15;
  const size_t base_bytes = (((size_t)(nB + 1) * 4) + 15) & ~(size_t)15;
  const size_t btot_bytes = (((size_t)nB * 4) + 15) & ~(size_t)15;
  const size_t wt_bytes   = (size_t)D * WTP * 2;
  const size_t tmp_bytes  = (size_t)nC * CE * 8;
  const size_t xb_bytes   = (size_t)nNodes * D * 2;
  const size_t ovl_bytes  = tmp_bytes > xb_bytes ? tmp_bytes : xb_bytes;
  const size_t need1 = csr_bytes + rs_bytes + ofs_bytes + base_bytes +
                       btot_bytes + wt_bytes + ovl_bytes;

  const int nchunks = (nNodes + CHUNK - 1) / CHUNK;
  const size_t e2_bytes  = (size_t)nE * 8;
  const size_t int_bytes = (size_t)(3 * nNodes + 1 + 2 * nchunks) * 4;
  const size_t need2 = e2_bytes + int_bytes;

  if (ws_size >= need1 && nNodes <= NB_MAX * 128 && nC <= MAXC) {
    char* p = (char*)d_ws;
    int2* csr = (int2*)p;                       p += csr_bytes;
    int* row_start = (int*)p;                   p += rs_bytes;
    unsigned short* ofs = (unsigned short*)p;   p += ofs_bytes;
    int* bases = (int*)p;                       p += base_bytes;
    int* btot = (int*)p;                        p += btot_bytes;
    unsigned short* wt = (unsigned short*)p;    p += wt_bytes;
    int2* tmp = (int2*)p;           // overlay: edges during CSR build,
    ushort4* xb4 = (ushort4*)p;     // then bf16 x-table for gather

    const int nxblk = (n4 + 255) / 256;
    chunk_sort_kernel<<<nC, 1024, 0, stream>>>(esrc, edst, adj, tmp, ofs, nE, nB);
    bucket_tot_kernel<<<nB, 256, 0, stream>>>(ofs, btot, nC, nB);
    scan_bases_kernel<<<1, 1024, 0, stream>>>(btot, bases, row_start, nB, nE,
                                              nNodes);
    bucket_csr_kernel<<<nB, 256, 0, stream>>>(tmp, ofs, bases, csr, row_start,
                                              nC, nB, nNodes);
    convert_kernel<<<nxblk + 64, 256, 0, stream>>>((const float4*)x, xb4, n4,
                                                   nxblk, w, wt);
    gather_pack_kernel<<<(nNodes * 32 + 255) / 256, 256, 0, stream>>>(
        (const uint2*)xb4, row_start, csr, (char*)d_out, nNodes);
    gemm_mfma_kernel<<<(nNodes + 127) / 128, 256, 0, stream>>>(
        (const char*)d_out, wt, y, bias, out, nNodes);
  } else if (ws_size >= need2) {
    char* base = (char*)d_ws;
    int2* edges = (int2*)base;
    int* counts = (int*)(base + e2_bytes);
    int* row_start = counts + nNodes;
    int* cursor = row_start + nNodes + 1;
    int* chunk_sum = cursor + nNodes;
    int* chunk_off = chunk_sum + nchunks;

    zero_counts_kernel<<<(nNodes + 255) / 256, 256, 0, stream>>>(counts, nNodes);
    hist_kernel<<<(nE + 255) / 256, 256, 0, stream>>>(edst, counts, nE);
    scan_partial_kernel<<<nchunks, 256, 0, stream>>>(counts, chunk_sum, nNodes);
    scan_chunks_kernel<<<1, 64, 0, stream>>>(chunk_sum, chunk_off, row_start,
                                             nchunks, nNodes);
    scan_final_kernel<<<nchunks, 256, 0, stream>>>(counts, chunk_off, row_start,
                                                   cursor, nNodes);
    scatter_sort_kernel<<<(nE + 255) / 256, 256, 0, stream>>>(
        esrc, edst, adj, cursor, edges, nE);
    gather_fp32_kernel<<<(nNodes * 32 + 255) / 256, 256, 0, stream>>>(
        x, row_start, edges, out, nNodes);
    gemm_fused_kernel<<<(nNodes + 31) / 32, 256, 0, stream>>>(out, w, y, bias,
                                                              nNodes);
  } else {
    zero_kernel<<<(n4 + 255) / 256, 256, 0, stream>>>((float4*)out, n4);
    scatter_atomic_kernel<<<((size_t)nE * 32 + 255) / 256, 256, 0, stream>>>(
        x, esrc, edst, adj, out, nE);
    gemm_fused_kernel<<<(nNodes + 31) / 32, 256, 0, stream>>>(out, w, y, bias,
                                                              nNodes);
  }
}